// Round 6
// baseline (235.841 us; speedup 1.0000x reference)
//
#include <hip/hip_runtime.h>
#include <hip/hip_bf16.h>

#define D_MODEL 1024
#define D_STATE 16
#define D_CONV 4
#define D_INNER 2048
#define DT_RANK 128
#define BATCH 2
#define SEQLEN 1024
#define XCOLS 160     // DT_RANK + 2*D_STATE
#define NCHUNK 32
#define LCHUNK 32     // SEQLEN / NCHUNK

typedef __hip_bfloat16 bf16;
typedef __attribute__((ext_vector_type(8))) short short8;
typedef __attribute__((ext_vector_type(4))) float f32x4;

__device__ __forceinline__ unsigned short f2bf_bits(float f) {
    bf16 h = __float2bfloat16(f);
    return *(unsigned short*)&h;
}

__device__ __forceinline__ float bfbits2f(short s) {
    union { float f; unsigned u; } v;
    v.u = ((unsigned)(unsigned short)s) << 16;
    return v.f;
}

__device__ __forceinline__ float softplus_f(float x) {
    return fmaxf(x, 0.f) + __logf(1.f + __expf(-fabsf(x)));
}

__device__ __forceinline__ float silu_f(float x) {
    return x / (1.f + __expf(-x));
}

// async global->LDS 16B per lane; LDS dest must be wave-uniform base + lane*16.
__device__ __forceinline__ void load16_lds(void* lds, const void* g) {
    __builtin_amdgcn_global_load_lds(
        (const __attribute__((address_space(1))) unsigned int*)g,
        (__attribute__((address_space(3))) unsigned int*)lds, 16, 0, 0);
}

// ---------------- fused prep: weight transposes + x convert + A precompute ----
__device__ __forceinline__ void transpose_tile(const float* __restrict__ B,
                                               bf16* __restrict__ Bt,
                                               int K, int N, int nt, int kt,
                                               float (*t)[33], int tid)
{
    const int tx = tid & 31, ty = tid >> 5;
    const int n0 = nt * 32, k0 = kt * 32;
    #pragma unroll
    for (int r = 0; r < 4; ++r) {
        int n = n0 + tx;
        t[ty + r * 8][tx] = (n < N) ? B[(size_t)(k0 + ty + r * 8) * N + n] : 0.f;
    }
    __syncthreads();
    #pragma unroll
    for (int r = 0; r < 4; ++r)
        Bt[(size_t)(n0 + ty + r * 8) * K + k0 + tx] = __float2bfloat16(t[tx][ty + r * 8]);
}

__global__ __launch_bounds__(256)
void prep_kernel(const float* __restrict__ x, bf16* __restrict__ x_bf,
                 const float* __restrict__ W_in, bf16* __restrict__ Win_t,
                 const float* __restrict__ W_xproj, bf16* __restrict__ Wxp_t,
                 const float* __restrict__ W_dt, bf16* __restrict__ Wdt_t,
                 const float* __restrict__ W_out, bf16* __restrict__ Wout_t,
                 const float* __restrict__ A_log, float* __restrict__ Aneg)
{
    __shared__ float t[32][33];
    const int tid = threadIdx.x;
    int blk = blockIdx.x;
    if (blk < 4096) {            // W_in: K=1024, Npad=4096 -> 128 x 32 tiles
        transpose_tile(W_in, Win_t, D_MODEL, 2 * D_INNER, blk & 127, blk >> 7, t, tid);
        return;
    }
    blk -= 4096;
    if (blk < 512) {             // W_xproj: K=2048, Npad=256 -> 8 x 64 tiles
        transpose_tile(W_xproj, Wxp_t, D_INNER, XCOLS, blk & 7, blk >> 3, t, tid);
        return;
    }
    blk -= 512;
    if (blk < 256) {             // W_dt: K=128, N=2048 -> 64 x 4 tiles
        transpose_tile(W_dt, Wdt_t, DT_RANK, D_INNER, blk & 63, blk >> 6, t, tid);
        return;
    }
    blk -= 256;
    if (blk < 2048) {            // W_out: K=2048, N=1024 -> 32 x 64 tiles
        transpose_tile(W_out, Wout_t, D_INNER, D_MODEL, blk & 31, blk >> 5, t, tid);
        return;
    }
    blk -= 2048;
    if (blk < 2048) {            // x -> bf16, float4
        int i = blk * 256 + tid;
        float4 v = ((const float4*)x)[i];
        ushort4 p;
        p.x = f2bf_bits(v.x); p.y = f2bf_bits(v.y);
        p.z = f2bf_bits(v.z); p.w = f2bf_bits(v.w);
        ((ushort4*)x_bf)[i] = p;
        return;
    }
    blk -= 2048;
    {                            // Aneg = -exp(A_log)
        int i = blk * 256 + tid;
        Aneg[i] = -__expf(A_log[i]);
    }
}

// ---------------- MFMA GEMM (tile 128xBN, BK=32, split-K capable) ------------
// 4-buffer depth-2 counted-vmcnt pipeline; chunk-XOR LDS swizzle; XCD remap.
// EPI=0: fp32 store to C. EPI=1: bf16 softplus(acc+bias) to Cb.
// EPI=2: cols [0,2048) -> bf16 to Cb2, cols [2048,4096) -> bf16 silu to Cb.
template<int BN, int EPI>
__global__ __launch_bounds__(256)
void gemm_mfma(const bf16* __restrict__ A, const bf16* __restrict__ Bt,
               float* __restrict__ C, bf16* __restrict__ Cb,
               bf16* __restrict__ Cb2,
               const float* __restrict__ bias,
               int M, int N, int K, int ldc, int kchunk)
{
    constexpr int WN = (BN == 128) ? 64 : 32;
    constexpr int NJ = WN / 16;
    __shared__ short As[4][128 * 32];
    __shared__ short Bs[4][BN * 32];
    const int tid = threadIdx.x;
    const int lane = tid & 63, wave = tid >> 6;
    const int wm = (wave >> 1) * 64, wn = (wave & 1) * WN;

    // XCD-chunked bijective remap (all our grids have total % 8 == 0).
    const int gx = gridDim.x, gy = gridDim.y;
    const int total = gx * gy * gridDim.z;
    const int hwid = (blockIdx.z * gy + blockIdx.y) * gx + blockIdx.x;
    const int nid = (hwid & 7) * (total >> 3) + (hwid >> 3);
    const int bz = nid / (gx * gy);
    const int rem = nid - bz * (gx * gy);
    const int bx = rem / gy;
    const int by = rem - bx * gy;

    const int row0 = by * 128, col0 = bx * BN;
    const int r_m = lane & 15, r_q = lane >> 4;
    const int kstart = bz * kchunk;
    float* Cz = C + (size_t)bz * M * ldc;

    // staging: thread t -> LDS shorts [8*tid, 8*tid+8) (linear dest required);
    // source chunk XOR-permuted so LDS[row][c] = G[row][c ^ (row&3)].
    const int srow = tid >> 2;
    const int schk = ((tid & 3) ^ (srow & 3)) * 8;
    const bf16* Ag0 = A  + (size_t)(row0 + srow)      * K + kstart + schk;
    const bf16* Ag1 = A  + (size_t)(row0 + srow + 64) * K + kstart + schk;
    const bf16* Bg0 = Bt + (size_t)(col0 + srow)      * K + kstart + schk;
    const bf16* Bg1 = Bt + (size_t)(col0 + srow + 64) * K + kstart + schk; // BN=128 only

    // ds_read chunk for the swizzle: row&3 == r_m&3 for every fragment row.
    const int cx = (r_q ^ (r_m & 3)) * 8;

    f32x4 acc[4][NJ];
    #pragma unroll
    for (int i = 0; i < 4; ++i)
        #pragma unroll
        for (int j = 0; j < NJ; ++j)
            #pragma unroll
            for (int r = 0; r < 4; ++r) acc[i][j][r] = 0.f;

#define GEMM_STAGE(BUF, KOFF)                                                   \
    {                                                                           \
        load16_lds(&As[BUF][8 * tid], Ag0 + (KOFF));                            \
        load16_lds(&As[BUF][8 * tid + 2048], Ag1 + (KOFF));                     \
        load16_lds(&Bs[BUF][8 * tid], Bg0 + (KOFF));                            \
        if (BN == 128) load16_lds(&Bs[BUF][8 * tid + 2048], Bg1 + (KOFF));      \
    }

#define GEMM_COMPUTE(BUF)                                                       \
    {                                                                           \
        short8 af[4], bfr[NJ];                                                  \
        _Pragma("unroll")                                                       \
        for (int i = 0; i < 4; ++i)                                             \
            af[i] = *(const short8*)&As[BUF][(wm + i * 16 + r_m) * 32 + cx];    \
        _Pragma("unroll")                                                       \
        for (int j = 0; j < NJ; ++j)                                            \
            bfr[j] = *(const short8*)&Bs[BUF][(wn + j * 16 + r_m) * 32 + cx];   \
        _Pragma("unroll")                                                       \
        for (int i = 0; i < 4; ++i)                                             \
            _Pragma("unroll")                                                   \
            for (int j = 0; j < NJ; ++j)                                        \
                acc[i][j] = __builtin_amdgcn_mfma_f32_16x16x32_bf16(            \
                    af[i], bfr[j], acc[i][j], 0, 0, 0);                         \
    }

#define WAITV(N) asm volatile("s_waitcnt vmcnt(" #N ")" ::: "memory")

    const int NT = kchunk >> 5;          // K-steps; >= 4 at every call site
    // prologue: two stages in flight
    GEMM_STAGE(0, 0);
    GEMM_STAGE(1, 32);
    for (int t = 0; t < NT - 1; ++t) {
        // wait for stage(t) only; stage(t+1) stays in flight across the barrier
        if constexpr (BN == 128) WAITV(4); else WAITV(3);
        __builtin_amdgcn_s_barrier();
        __builtin_amdgcn_sched_barrier(0);
        if (t + 2 < NT) GEMM_STAGE((t + 2) & 3, (t + 2) * 32);
        GEMM_COMPUTE(t & 3);
    }
    WAITV(0);
    __builtin_amdgcn_s_barrier();
    __builtin_amdgcn_sched_barrier(0);
    GEMM_COMPUTE((NT - 1) & 3);
#undef GEMM_STAGE
#undef GEMM_COMPUTE
#undef WAITV

    #pragma unroll
    for (int i = 0; i < 4; ++i) {
        #pragma unroll
        for (int j = 0; j < NJ; ++j) {
            int row = row0 + wm + i * 16 + r_q * 4;
            int col = col0 + wn + j * 16 + r_m;
            if (col < N) {
                if (EPI == 1) {
                    float bv = bias[col];
                    #pragma unroll
                    for (int r = 0; r < 4; ++r)
                        Cb[(size_t)(row + r) * ldc + col] =
                            __float2bfloat16(softplus_f(acc[i][j][r] + bv));
                } else if (EPI == 2) {
                    if (col < 2048) {        // x half -> bf16 (conv input)
                        #pragma unroll
                        for (int r = 0; r < 4; ++r)
                            Cb2[(size_t)(row + r) * ldc + col] =
                                __float2bfloat16(acc[i][j][r]);
                    } else {                 // z half -> bf16 silu(z)
                        int zc = col - 2048;
                        #pragma unroll
                        for (int r = 0; r < 4; ++r)
                            Cb[(size_t)(row + r) * ldc + zc] =
                                __float2bfloat16(silu_f(acc[i][j][r]));
                    }
                } else {
                    #pragma unroll
                    for (int r = 0; r < 4; ++r)
                        Cz[(size_t)(row + r) * ldc + col] = acc[i][j][r];
                }
            }
        }
    }
}

// reduce 8 split-K partials (ldc=256) -> x_dbl fp32 (160 cols) + dt_low bf16
__global__ __launch_bounds__(256)
void reduce_xdbl(const float* __restrict__ Cpart, float* __restrict__ x_dbl,
                 bf16* __restrict__ dtA_bf)
{
    int i4 = blockIdx.x * 256 + threadIdx.x;         // 2048 * 40 float4-groups
    if (i4 >= 2048 * (XCOLS / 4)) return;
    int r = i4 / (XCOLS / 4), c4 = i4 - r * (XCOLS / 4);
    float4 s = {0.f, 0.f, 0.f, 0.f};
    #pragma unroll
    for (int z = 0; z < 8; ++z) {
        float4 v = *(const float4*)&Cpart[(size_t)z * 2048 * 256 + (size_t)r * 256 + c4 * 4];
        s.x += v.x; s.y += v.y; s.z += v.z; s.w += v.w;
    }
    *(float4*)&x_dbl[(size_t)r * XCOLS + c4 * 4] = s;
    if (c4 < DT_RANK / 4) {
        ushort4 p;
        p.x = f2bf_bits(s.x); p.y = f2bf_bits(s.y);
        p.z = f2bf_bits(s.z); p.w = f2bf_bits(s.w);
        *(ushort4*)&dtA_bf[(size_t)r * DT_RANK + c4 * 4] = p;
    }
}

// ---------------- conv + silu (short8 over d), bf16 in / bf16 out ------------
// xd is dense [B*L][D_INNER] bf16 (the x half of in_proj).
__global__ __launch_bounds__(256)
void conv_silu_kernel(const bf16* __restrict__ xd,
                      const float* __restrict__ conv_k,
                      const float* __restrict__ conv_b,
                      bf16* __restrict__ u_bf)
{
    int idx8 = blockIdx.x * 256 + threadIdx.x;       // B*L*Di/8 = 524288
    int d8 = idx8 & (D_INNER / 8 - 1);
    int t = (idx8 >> 8) & (SEQLEN - 1);
    int b = idx8 >> 18;
    float acc[8];
    {
        float4 b0 = ((const float4*)conv_b)[d8 * 2];
        float4 b1 = ((const float4*)conv_b)[d8 * 2 + 1];
        acc[0] = b0.x; acc[1] = b0.y; acc[2] = b0.z; acc[3] = b0.w;
        acc[4] = b1.x; acc[5] = b1.y; acc[6] = b1.z; acc[7] = b1.w;
    }
    #pragma unroll
    for (int k = 0; k < D_CONV; ++k) {
        int tt = t + k - (D_CONV - 1);
        if (tt >= 0) {
            short8 xv = ((const short8*)xd)[(size_t)(b * SEQLEN + tt) * (D_INNER / 8) + d8];
            float4 k0 = ((const float4*)conv_k)[k * (D_INNER / 4) + d8 * 2];
            float4 k1 = ((const float4*)conv_k)[k * (D_INNER / 4) + d8 * 2 + 1];
            acc[0] = fmaf(bfbits2f(xv[0]), k0.x, acc[0]);
            acc[1] = fmaf(bfbits2f(xv[1]), k0.y, acc[1]);
            acc[2] = fmaf(bfbits2f(xv[2]), k0.z, acc[2]);
            acc[3] = fmaf(bfbits2f(xv[3]), k0.w, acc[3]);
            acc[4] = fmaf(bfbits2f(xv[4]), k1.x, acc[4]);
            acc[5] = fmaf(bfbits2f(xv[5]), k1.y, acc[5]);
            acc[6] = fmaf(bfbits2f(xv[6]), k1.z, acc[6]);
            acc[7] = fmaf(bfbits2f(xv[7]), k1.w, acc[7]);
        }
    }
    short8 r;
    #pragma unroll
    for (int j = 0; j < 8; ++j)
        r[j] = (short)f2bf_bits(acc[j] / (1.f + __expf(-acc[j])));
    ((short8*)u_bf)[idx8] = r;
}

// ---------------- chunked scan ----------------
// dt_sb = bf16 softplus(dt_pre + b_dt) (GEMM4 epilogue).
__global__ __launch_bounds__(256)
void scan_phase1(const bf16* __restrict__ dt_sb,
                 const float* __restrict__ Aneg,
                 const bf16* __restrict__ u_bf,
                 const float* __restrict__ x_dbl,
                 float* __restrict__ Pst, float* __restrict__ Sst)
{
    __shared__ float Bsm[LCHUNK][16];
    const int d = blockIdx.x * 256 + threadIdx.x;
    const int c = blockIdx.y, b = blockIdx.z;
    const int t0 = c * LCHUNK;
    for (int i = threadIdx.x; i < LCHUNK * 16; i += 256) {   // stage B rows
        int tt = i >> 4, n = i & 15;
        Bsm[tt][n] = x_dbl[(size_t)(b * SEQLEN + t0 + tt) * XCOLS + DT_RANK + n];
    }
    float A_row[D_STATE];
    const float4* a4 = (const float4*)(Aneg + d * D_STATE);
    #pragma unroll
    for (int q = 0; q < 4; ++q) {
        float4 v = a4[q];
        A_row[q*4+0] = v.x; A_row[q*4+1] = v.y; A_row[q*4+2] = v.z; A_row[q*4+3] = v.w;
    }
    __syncthreads();
    float P[D_STATE], S[D_STATE];
    #pragma unroll
    for (int n = 0; n < D_STATE; ++n) { P[n] = 1.f; S[n] = 0.f; }
    const bf16* dpp = dt_sb + (size_t)(b * SEQLEN + t0) * D_INNER + d;
    const bf16* upp = u_bf + (size_t)(b * SEQLEN + t0) * D_INNER + d;
    #pragma unroll 4
    for (int t = 0; t < LCHUNK; ++t) {
        float dtv = __bfloat162float(dpp[(size_t)t * D_INNER]);
        float du = dtv * __bfloat162float(upp[(size_t)t * D_INNER]);
        const float4* b4 = (const float4*)&Bsm[t][0];
        #pragma unroll
        for (int q = 0; q < 4; ++q) {
            float4 v = b4[q];
            float Bn[4] = {v.x, v.y, v.z, v.w};
            #pragma unroll
            for (int e = 0; e < 4; ++e) {
                int n = q * 4 + e;
                float a = __expf(dtv * A_row[n]);
                P[n] *= a;
                S[n] = fmaf(a, S[n], du * Bn[e]);
            }
        }
    }
    const size_t base = ((size_t)(b * NCHUNK + c) * D_STATE) * D_INNER + d;
    #pragma unroll
    for (int n = 0; n < D_STATE; ++n) {
        Pst[base + (size_t)n * D_INNER] = P[n];
        Sst[base + (size_t)n * D_INNER] = S[n];
    }
}

// Phase 2: combine chunk transforms; write h_in per chunk IN-PLACE over Sst.
// All loads address-independent: preload into regs, chain in-register.
__global__ __launch_bounds__(256)
void scan_phase2(const float* __restrict__ Pst, float* __restrict__ Sst)
{
    const int d = blockIdx.x * 256 + threadIdx.x;
    const int n = blockIdx.y;
    const int b = blockIdx.z;
    float Pv[NCHUNK], Sv[NCHUNK];
    #pragma unroll
    for (int c = 0; c < NCHUNK; ++c) {
        const size_t idx = ((size_t)(b * NCHUNK + c) * D_STATE + n) * D_INNER + d;
        Pv[c] = Pst[idx];
        Sv[c] = Sst[idx];
    }
    float h = 0.f;
    #pragma unroll
    for (int c = 0; c < NCHUNK; ++c) {
        float hin = h;
        h = fmaf(Pv[c], h, Sv[c]);
        Sv[c] = hin;                        // h_in for chunk c
    }
    #pragma unroll
    for (int c = 0; c < NCHUNK; ++c) {
        const size_t idx = ((size_t)(b * NCHUNK + c) * D_STATE + n) * D_INNER + d;
        Sst[idx] = Sv[c];
    }
}

__global__ __launch_bounds__(256)
void scan_phase3(const bf16* __restrict__ dt_sb,
                 const float* __restrict__ Aneg,
                 const bf16* __restrict__ u_bf,
                 const float* __restrict__ x_dbl,
                 const float* __restrict__ Dvec,
                 const bf16* __restrict__ sz_bf,  // silu(z), bf16
                 const float* __restrict__ hin,   // == Sst after phase2
                 bf16* __restrict__ g_bf)
{
    __shared__ float BCs[LCHUNK][32];
    const int d = blockIdx.x * 256 + threadIdx.x;
    const int c = blockIdx.y, b = blockIdx.z;
    const int t0 = c * LCHUNK;
    for (int i = threadIdx.x; i < LCHUNK * 32; i += 256) {   // stage B and C rows
        int tt = i >> 5, col = i & 31;
        BCs[tt][col] = x_dbl[(size_t)(b * SEQLEN + t0 + tt) * XCOLS + DT_RANK + col];
    }
    float A_row[D_STATE];
    const float4* a4 = (const float4*)(Aneg + d * D_STATE);
    #pragma unroll
    for (int q = 0; q < 4; ++q) {
        float4 v = a4[q];
        A_row[q*4+0] = v.x; A_row[q*4+1] = v.y; A_row[q*4+2] = v.z; A_row[q*4+3] = v.w;
    }
    const float Dd = Dvec[d];
    __syncthreads();
    float h[D_STATE];
    const size_t base = ((size_t)(b * NCHUNK + c) * D_STATE) * D_INNER + d;
    #pragma unroll
    for (int n = 0; n < D_STATE; ++n) h[n] = hin[base + (size_t)n * D_INNER];
    const bf16* dpp = dt_sb + (size_t)(b * SEQLEN + t0) * D_INNER + d;
    const bf16* upp = u_bf + (size_t)(b * SEQLEN + t0) * D_INNER + d;
    const bf16* zpp = sz_bf + (size_t)(b * SEQLEN + t0) * D_INNER + d;
    bf16* gpp = g_bf + (size_t)(b * SEQLEN + t0) * D_INNER + d;
    #pragma unroll 4
    for (int t = 0; t < LCHUNK; ++t) {
        float dtv = __bfloat162float(dpp[(size_t)t * D_INNER]);
        float uv = __bfloat162float(upp[(size_t)t * D_INNER]);
        float sz = __bfloat162float(zpp[(size_t)t * D_INNER]);
        float du = dtv * uv;
        float y = 0.f;
        const float4* bc4 = (const float4*)&BCs[t][0];
        #pragma unroll
        for (int q = 0; q < 4; ++q) {
            float4 v = bc4[q];
            float4 w = bc4[q + 4];
            float Bn[4] = {v.x, v.y, v.z, v.w};
            float Cn[4] = {w.x, w.y, w.z, w.w};
            #pragma unroll
            for (int e = 0; e < 4; ++e) {
                int n = q * 4 + e;
                float a = __expf(dtv * A_row[n]);
                h[n] = fmaf(a, h[n], du * Bn[e]);
                y = fmaf(h[n], Cn[e], y);
            }
        }
        float gy = y + uv * Dd;
        gpp[(size_t)t * D_INNER] = __float2bfloat16(gy * sz);
    }
}

extern "C" void kernel_launch(void* const* d_in, const int* in_sizes, int n_in,
                              void* d_out, int out_size, void* d_ws, size_t ws_size,
                              hipStream_t stream)
{
    const float* x      = (const float*)d_in[0];
    const float* W_in   = (const float*)d_in[1];
    const float* conv_k = (const float*)d_in[2];
    const float* conv_b = (const float*)d_in[3];
    const float* W_xproj= (const float*)d_in[4];
    const float* W_dt   = (const float*)d_in[5];
    const float* b_dt   = (const float*)d_in[6];
    const float* A_log  = (const float*)d_in[7];
    const float* Dvec   = (const float*)d_in[8];
    const float* W_out  = (const float*)d_in[9];
    float* out = (float*)d_out;

    const int BL = BATCH * SEQLEN;                    // 2048

    // fp32 region
    float* ws     = (float*)d_ws;
    float* x_dbl  = ws;                                 //   327,680
    float* Pst    = x_dbl + (size_t)BL * XCOLS;         // 2,097,152
    float* Sst    = Pst + (size_t)BATCH * NCHUNK * D_STATE * D_INNER;   // 2,097,152
    float* Aneg   = Sst + (size_t)BATCH * NCHUNK * D_STATE * D_INNER;   //    32,768
    float* Cpart  = Aneg + 32768;                       // 4,194,304 floats (GEMM3: 8x2048x256)
    bf16*  x_bf   = (bf16*)Cpart;                       // 2048x1024, dead before GEMM3
    // bf16 region
    bf16* Win_t  = (bf16*)(Cpart + (size_t)4 * 1048576);// 4096 x 1024
    bf16* xd_bf  = Win_t + (size_t)4096 * 1024;         // 2048 x 2048 (x half, bf16)
    bf16* u_bf   = xd_bf + (size_t)BL * D_INNER;        // 2048 x 2048
    bf16* sz_bf  = u_bf  + (size_t)BL * D_INNER;        // 2048 x 2048 (silu(z))
    bf16* Wxp_t  = sz_bf + (size_t)BL * D_INNER;        // 256  x 2048 (padded)
    bf16* dtA_bf = Wxp_t + (size_t)256 * 2048;          // 2048 x 128
    bf16* Wdt_t  = dtA_bf+ (size_t)BL * DT_RANK;        // 2048 x 128
    bf16* g_bf   = Wdt_t + (size_t)2048 * 128;          // 2048 x 2048
    bf16* Wout_t = g_bf  + (size_t)BL * D_INNER;        // 1024 x 2048
    bf16* dt_sb  = Wout_t+ (size_t)1024 * 2048;         // 2048 x 2048

    // 0) fused prep: 4 transposes + x convert + Aneg
    prep_kernel<<<4096 + 512 + 256 + 2048 + 2048 + 128, 256, 0, stream>>>(
        x, x_bf, W_in, Win_t, W_xproj, Wxp_t, W_dt, Wdt_t, W_out, Wout_t, A_log, Aneg);

    // 1) in_proj: x part -> xd_bf bf16 [2048][2048]; z part -> sz_bf = bf16(silu(z))
    gemm_mfma<128, 2><<<dim3(32, 16, 1), 256, 0, stream>>>(
        x_bf, Win_t, nullptr, sz_bf, xd_bf, nullptr, BL, 2 * D_INNER, D_MODEL, D_INNER, D_MODEL);

    // 2) u_bf = bf16(silu(causal_conv(xd_bf) + b))
    conv_silu_kernel<<<(BL * D_INNER / 8) / 256, 256, 0, stream>>>(xd_bf, conv_k, conv_b, u_bf);

    // 3) x_dbl = u @ W_xproj  split-K 8, BN=64, 3 col-blocks (cols 0..191 cover 160)
    gemm_mfma<64, 0><<<dim3(3, 16, 8), 256, 0, stream>>>(
        u_bf, Wxp_t, Cpart, nullptr, nullptr, nullptr, BL, 256, D_INNER, 256, 256);
    reduce_xdbl<<<(BL * (XCOLS / 4) + 255) / 256, 256, 0, stream>>>(Cpart, x_dbl, dtA_bf);

    // 4) dt_sb = bf16(softplus(dt_low @ W_dt + b_dt)), BN=64 -> 512 blocks
    gemm_mfma<64, 1><<<dim3(32, 16, 1), 256, 0, stream>>>(
        dtA_bf, Wdt_t, nullptr, dt_sb, nullptr, b_dt, BL, D_INNER, DT_RANK, D_INNER, DT_RANK);

    // 5) chunked selective scan -> g_bf = bf16((y + u*D) * silu(z))
    scan_phase1<<<dim3(D_INNER / 256, NCHUNK, BATCH), 256, 0, stream>>>(
        dt_sb, Aneg, u_bf, x_dbl, Pst, Sst);
    scan_phase2<<<dim3(D_INNER / 256, D_STATE, BATCH), 256, 0, stream>>>(Pst, Sst);
    scan_phase3<<<dim3(D_INNER / 256, NCHUNK, BATCH), 256, 0, stream>>>(
        dt_sb, Aneg, u_bf, x_dbl, Dvec, sz_bf, Sst, g_bf);

    // 6) out = g @ W_out  single chunk (K=2048), 256 blocks, direct fp32 -> out
    gemm_mfma<64, 0><<<dim3(16, 16, 1), 256, 0, stream>>>(
        g_bf, Wout_t, out, nullptr, nullptr, nullptr, BL, D_MODEL, D_INNER, D_MODEL, D_INNER);
}

// Round 7
// 229.454 us; speedup vs baseline: 1.0278x; 1.0278x over previous
//
#include <hip/hip_runtime.h>
#include <hip/hip_bf16.h>

#define D_MODEL 1024
#define D_STATE 16
#define D_CONV 4
#define D_INNER 2048
#define DT_RANK 128
#define BATCH 2
#define SEQLEN 1024
#define XCOLS 160     // DT_RANK + 2*D_STATE
#define NCHUNK 32
#define LCHUNK 32     // SEQLEN / NCHUNK

typedef __hip_bfloat16 bf16;
typedef __attribute__((ext_vector_type(8))) short short8;
typedef __attribute__((ext_vector_type(4))) float f32x4;

__device__ __forceinline__ unsigned short f2bf_bits(float f) {
    bf16 h = __float2bfloat16(f);
    return *(unsigned short*)&h;
}

__device__ __forceinline__ float bfbits2f(short s) {
    union { float f; unsigned u; } v;
    v.u = ((unsigned)(unsigned short)s) << 16;
    return v.f;
}

__device__ __forceinline__ float softplus_f(float x) {
    return fmaxf(x, 0.f) + __logf(1.f + __expf(-fabsf(x)));
}

__device__ __forceinline__ float silu_f(float x) {
    return x / (1.f + __expf(-x));
}

// async global->LDS 16B per lane; LDS dest must be wave-uniform base + lane*16.
__device__ __forceinline__ void load16_lds(void* lds, const void* g) {
    __builtin_amdgcn_global_load_lds(
        (const __attribute__((address_space(1))) unsigned int*)g,
        (__attribute__((address_space(3))) unsigned int*)lds, 16, 0, 0);
}

// ---------------- fused prep: weight transposes + x convert + A precompute ----
__device__ __forceinline__ void transpose_tile(const float* __restrict__ B,
                                               bf16* __restrict__ Bt,
                                               int K, int N, int nt, int kt,
                                               float (*t)[33], int tid)
{
    const int tx = tid & 31, ty = tid >> 5;
    const int n0 = nt * 32, k0 = kt * 32;
    #pragma unroll
    for (int r = 0; r < 4; ++r) {
        int n = n0 + tx;
        t[ty + r * 8][tx] = (n < N) ? B[(size_t)(k0 + ty + r * 8) * N + n] : 0.f;
    }
    __syncthreads();
    #pragma unroll
    for (int r = 0; r < 4; ++r)
        Bt[(size_t)(n0 + ty + r * 8) * K + k0 + tx] = __float2bfloat16(t[tx][ty + r * 8]);
}

__global__ __launch_bounds__(256)
void prep_kernel(const float* __restrict__ x, bf16* __restrict__ x_bf,
                 const float* __restrict__ W_in, bf16* __restrict__ Win_t,
                 const float* __restrict__ W_xproj, bf16* __restrict__ Wxp_t,
                 const float* __restrict__ W_dt, bf16* __restrict__ Wdt_t,
                 const float* __restrict__ W_out, bf16* __restrict__ Wout_t,
                 const float* __restrict__ A_log, float* __restrict__ Aneg)
{
    __shared__ float t[32][33];
    const int tid = threadIdx.x;
    int blk = blockIdx.x;
    if (blk < 4096) {            // W_in: K=1024, Npad=4096 -> 128 x 32 tiles
        transpose_tile(W_in, Win_t, D_MODEL, 2 * D_INNER, blk & 127, blk >> 7, t, tid);
        return;
    }
    blk -= 4096;
    if (blk < 512) {             // W_xproj: K=2048, Npad=256 -> 8 x 64 tiles
        transpose_tile(W_xproj, Wxp_t, D_INNER, XCOLS, blk & 7, blk >> 3, t, tid);
        return;
    }
    blk -= 512;
    if (blk < 256) {             // W_dt: K=128, N=2048 -> 64 x 4 tiles
        transpose_tile(W_dt, Wdt_t, DT_RANK, D_INNER, blk & 63, blk >> 6, t, tid);
        return;
    }
    blk -= 256;
    if (blk < 2048) {            // W_out: K=2048, N=1024 -> 32 x 64 tiles
        transpose_tile(W_out, Wout_t, D_INNER, D_MODEL, blk & 31, blk >> 5, t, tid);
        return;
    }
    blk -= 2048;
    if (blk < 2048) {            // x -> bf16, float4
        int i = blk * 256 + tid;
        float4 v = ((const float4*)x)[i];
        ushort4 p;
        p.x = f2bf_bits(v.x); p.y = f2bf_bits(v.y);
        p.z = f2bf_bits(v.z); p.w = f2bf_bits(v.w);
        ((ushort4*)x_bf)[i] = p;
        return;
    }
    blk -= 2048;
    {                            // Aneg = -exp(A_log)
        int i = blk * 256 + tid;
        Aneg[i] = -__expf(A_log[i]);
    }
}

// ---------------- MFMA GEMM (tile 128xBN, BK=32, split-K capable) ------------
// 2-phase double-buffered pipeline (R3 schedule — best measured): stage(t+1)
// issued BEFORE compute(t); one __syncthreads per K-step.
// LDS swizzle: chunk s = base ^ ((row>>1)&3) -> 2-way bank access (free, m136).
// XCD-chunked bijective block remap.
// EPI=0: fp32 store to C. EPI=1: bf16 softplus(acc+bias) to Cb.
// EPI=2: cols [0,2048) -> bf16 to Cb2, cols [2048,4096) -> bf16 silu to Cb.
template<int BN, int EPI>
__global__ __launch_bounds__(256)
void gemm_mfma(const bf16* __restrict__ A, const bf16* __restrict__ Bt,
               float* __restrict__ C, bf16* __restrict__ Cb,
               bf16* __restrict__ Cb2,
               const float* __restrict__ bias,
               int M, int N, int K, int ldc, int kchunk)
{
    constexpr int WN = (BN == 128) ? 64 : 32;
    constexpr int NJ = WN / 16;
    __shared__ short As[2][128 * 32];
    __shared__ short Bs[2][BN * 32];
    const int tid = threadIdx.x;
    const int lane = tid & 63, wave = tid >> 6;
    const int wm = (wave >> 1) * 64, wn = (wave & 1) * WN;

    // XCD-chunked bijective remap (all our grids have total % 8 == 0).
    const int gx = gridDim.x, gy = gridDim.y;
    const int total = gx * gy * gridDim.z;
    const int hwid = (blockIdx.z * gy + blockIdx.y) * gx + blockIdx.x;
    const int nid = (hwid & 7) * (total >> 3) + (hwid >> 3);
    const int bz = nid / (gx * gy);
    const int rem = nid - bz * (gx * gy);
    const int bx = rem / gy;
    const int by = rem - bx * gy;

    const int row0 = by * 128, col0 = bx * BN;
    const int r_m = lane & 15, r_q = lane >> 4;
    const int kstart = bz * kchunk;
    float* Cz = C + (size_t)bz * M * ldc;

    // staging: thread t -> LDS shorts [8*tid, 8*tid+8) (linear dest required);
    // source chunk XOR-permuted: LDS[row][c] = G[row][c ^ ((row>>1)&3)].
    // Row stride 64B => bank slot = 64*(row&1) + 16*s mod 128; s=(row>>1)&3
    // spreads 16 fragment rows over all 8 slots -> 2-way (free).
    const int srow = tid >> 2;
    const int schk = ((tid & 3) ^ ((srow >> 1) & 3)) * 8;
    const bf16* Ag0 = A  + (size_t)(row0 + srow)      * K + kstart + schk;
    const bf16* Ag1 = A  + (size_t)(row0 + srow + 64) * K + kstart + schk; // sigma(srow+64)==sigma(srow)
    const bf16* Bg0 = Bt + (size_t)(col0 + srow)      * K + kstart + schk;
    const bf16* Bg1 = Bt + (size_t)(col0 + srow + 64) * K + kstart + schk; // BN=128 only

    // ds_read chunk: row = (mult of 16) + r_m => (row>>1)&3 == (r_m>>1)&3.
    const int cx = (r_q ^ ((r_m >> 1) & 3)) * 8;

    f32x4 acc[4][NJ];
    #pragma unroll
    for (int i = 0; i < 4; ++i)
        #pragma unroll
        for (int j = 0; j < NJ; ++j)
            #pragma unroll
            for (int r = 0; r < 4; ++r) acc[i][j][r] = 0.f;

#define GEMM_STAGE(BUF, KOFF)                                                   \
    {                                                                           \
        load16_lds(&As[BUF][8 * tid], Ag0 + (KOFF));                            \
        load16_lds(&As[BUF][8 * tid + 2048], Ag1 + (KOFF));                     \
        load16_lds(&Bs[BUF][8 * tid], Bg0 + (KOFF));                            \
        if (BN == 128) load16_lds(&Bs[BUF][8 * tid + 2048], Bg1 + (KOFF));      \
    }

#define GEMM_COMPUTE(BUF)                                                       \
    {                                                                           \
        short8 af[4], bfr[NJ];                                                  \
        _Pragma("unroll")                                                       \
        for (int i = 0; i < 4; ++i)                                             \
            af[i] = *(const short8*)&As[BUF][(wm + i * 16 + r_m) * 32 + cx];    \
        _Pragma("unroll")                                                       \
        for (int j = 0; j < NJ; ++j)                                            \
            bfr[j] = *(const short8*)&Bs[BUF][(wn + j * 16 + r_m) * 32 + cx];   \
        _Pragma("unroll")                                                       \
        for (int i = 0; i < 4; ++i)                                             \
            _Pragma("unroll")                                                   \
            for (int j = 0; j < NJ; ++j)                                        \
                acc[i][j] = __builtin_amdgcn_mfma_f32_16x16x32_bf16(            \
                    af[i], bfr[j], acc[i][j], 0, 0, 0);                         \
    }

    // prologue
    GEMM_STAGE(0, 0);
    __syncthreads();                     // vmcnt drained -> buf0 visible
    // main loop: kchunk % 64 == 0 for all call sites (128/256/1024)
    for (int k0 = 0; k0 < kchunk; k0 += 64) {
        GEMM_STAGE(1, k0 + 32);          // prefetch overlaps compute(0)
        GEMM_COMPUTE(0);
        __syncthreads();                 // drains vmcnt -> buf1 visible; buf0 reads done
        if (k0 + 64 < kchunk) GEMM_STAGE(0, k0 + 64);
        GEMM_COMPUTE(1);
        __syncthreads();
    }
#undef GEMM_STAGE
#undef GEMM_COMPUTE

    #pragma unroll
    for (int i = 0; i < 4; ++i) {
        #pragma unroll
        for (int j = 0; j < NJ; ++j) {
            int row = row0 + wm + i * 16 + r_q * 4;
            int col = col0 + wn + j * 16 + r_m;
            if (col < N) {
                if (EPI == 1) {
                    float bv = bias[col];
                    #pragma unroll
                    for (int r = 0; r < 4; ++r)
                        Cb[(size_t)(row + r) * ldc + col] =
                            __float2bfloat16(softplus_f(acc[i][j][r] + bv));
                } else if (EPI == 2) {
                    if (col < 2048) {        // x half -> bf16 (conv input)
                        #pragma unroll
                        for (int r = 0; r < 4; ++r)
                            Cb2[(size_t)(row + r) * ldc + col] =
                                __float2bfloat16(acc[i][j][r]);
                    } else {                 // z half -> bf16 silu(z)
                        int zc = col - 2048;
                        #pragma unroll
                        for (int r = 0; r < 4; ++r)
                            Cb[(size_t)(row + r) * ldc + zc] =
                                __float2bfloat16(silu_f(acc[i][j][r]));
                    }
                } else {
                    #pragma unroll
                    for (int r = 0; r < 4; ++r)
                        Cz[(size_t)(row + r) * ldc + col] = acc[i][j][r];
                }
            }
        }
    }
}

// reduce 8 split-K partials (ldc=256) -> x_dbl fp32 (160 cols) + dt_low bf16
__global__ __launch_bounds__(256)
void reduce_xdbl(const float* __restrict__ Cpart, float* __restrict__ x_dbl,
                 bf16* __restrict__ dtA_bf)
{
    int i4 = blockIdx.x * 256 + threadIdx.x;         // 2048 * 40 float4-groups
    if (i4 >= 2048 * (XCOLS / 4)) return;
    int r = i4 / (XCOLS / 4), c4 = i4 - r * (XCOLS / 4);
    float4 s = {0.f, 0.f, 0.f, 0.f};
    #pragma unroll
    for (int z = 0; z < 8; ++z) {
        float4 v = *(const float4*)&Cpart[(size_t)z * 2048 * 256 + (size_t)r * 256 + c4 * 4];
        s.x += v.x; s.y += v.y; s.z += v.z; s.w += v.w;
    }
    *(float4*)&x_dbl[(size_t)r * XCOLS + c4 * 4] = s;
    if (c4 < DT_RANK / 4) {
        ushort4 p;
        p.x = f2bf_bits(s.x); p.y = f2bf_bits(s.y);
        p.z = f2bf_bits(s.z); p.w = f2bf_bits(s.w);
        *(ushort4*)&dtA_bf[(size_t)r * DT_RANK + c4 * 4] = p;
    }
}

// reduce 2 split-K partials -> out fp32, float4
__global__ __launch_bounds__(256)
void reduce_out(const float* __restrict__ Cpart, float* __restrict__ out)
{
    int i = blockIdx.x * 256 + threadIdx.x;          // (2048*1024)/4
    const float4* p0 = (const float4*)Cpart;
    const float4* p1 = p0 + (size_t)2048 * 1024 / 4;
    float4 a = p0[i], b = p1[i];
    float4 r; r.x = a.x + b.x; r.y = a.y + b.y; r.z = a.z + b.z; r.w = a.w + b.w;
    ((float4*)out)[i] = r;
}

// ---------------- conv + silu (short8 over d), bf16 in / bf16 out ------------
// xd is dense [B*L][D_INNER] bf16 (the x half of in_proj).
__global__ __launch_bounds__(256)
void conv_silu_kernel(const bf16* __restrict__ xd,
                      const float* __restrict__ conv_k,
                      const float* __restrict__ conv_b,
                      bf16* __restrict__ u_bf)
{
    int idx8 = blockIdx.x * 256 + threadIdx.x;       // B*L*Di/8 = 524288
    int d8 = idx8 & (D_INNER / 8 - 1);
    int t = (idx8 >> 8) & (SEQLEN - 1);
    int b = idx8 >> 18;
    float acc[8];
    {
        float4 b0 = ((const float4*)conv_b)[d8 * 2];
        float4 b1 = ((const float4*)conv_b)[d8 * 2 + 1];
        acc[0] = b0.x; acc[1] = b0.y; acc[2] = b0.z; acc[3] = b0.w;
        acc[4] = b1.x; acc[5] = b1.y; acc[6] = b1.z; acc[7] = b1.w;
    }
    #pragma unroll
    for (int k = 0; k < D_CONV; ++k) {
        int tt = t + k - (D_CONV - 1);
        if (tt >= 0) {
            short8 xv = ((const short8*)xd)[(size_t)(b * SEQLEN + tt) * (D_INNER / 8) + d8];
            float4 k0 = ((const float4*)conv_k)[k * (D_INNER / 4) + d8 * 2];
            float4 k1 = ((const float4*)conv_k)[k * (D_INNER / 4) + d8 * 2 + 1];
            acc[0] = fmaf(bfbits2f(xv[0]), k0.x, acc[0]);
            acc[1] = fmaf(bfbits2f(xv[1]), k0.y, acc[1]);
            acc[2] = fmaf(bfbits2f(xv[2]), k0.z, acc[2]);
            acc[3] = fmaf(bfbits2f(xv[3]), k0.w, acc[3]);
            acc[4] = fmaf(bfbits2f(xv[4]), k1.x, acc[4]);
            acc[5] = fmaf(bfbits2f(xv[5]), k1.y, acc[5]);
            acc[6] = fmaf(bfbits2f(xv[6]), k1.z, acc[6]);
            acc[7] = fmaf(bfbits2f(xv[7]), k1.w, acc[7]);
        }
    }
    short8 r;
    #pragma unroll
    for (int j = 0; j < 8; ++j)
        r[j] = (short)f2bf_bits(acc[j] / (1.f + __expf(-acc[j])));
    ((short8*)u_bf)[idx8] = r;
}

// ---------------- chunked scan ----------------
// dt_sb = bf16 softplus(dt_pre + b_dt) (GEMM4 epilogue).
__global__ __launch_bounds__(256)
void scan_phase1(const bf16* __restrict__ dt_sb,
                 const float* __restrict__ Aneg,
                 const bf16* __restrict__ u_bf,
                 const float* __restrict__ x_dbl,
                 float* __restrict__ Pst, float* __restrict__ Sst)
{
    __shared__ float Bsm[LCHUNK][16];
    const int d = blockIdx.x * 256 + threadIdx.x;
    const int c = blockIdx.y, b = blockIdx.z;
    const int t0 = c * LCHUNK;
    for (int i = threadIdx.x; i < LCHUNK * 16; i += 256) {   // stage B rows
        int tt = i >> 4, n = i & 15;
        Bsm[tt][n] = x_dbl[(size_t)(b * SEQLEN + t0 + tt) * XCOLS + DT_RANK + n];
    }
    float A_row[D_STATE];
    const float4* a4 = (const float4*)(Aneg + d * D_STATE);
    #pragma unroll
    for (int q = 0; q < 4; ++q) {
        float4 v = a4[q];
        A_row[q*4+0] = v.x; A_row[q*4+1] = v.y; A_row[q*4+2] = v.z; A_row[q*4+3] = v.w;
    }
    __syncthreads();
    float P[D_STATE], S[D_STATE];
    #pragma unroll
    for (int n = 0; n < D_STATE; ++n) { P[n] = 1.f; S[n] = 0.f; }
    const bf16* dpp = dt_sb + (size_t)(b * SEQLEN + t0) * D_INNER + d;
    const bf16* upp = u_bf + (size_t)(b * SEQLEN + t0) * D_INNER + d;
    #pragma unroll 4
    for (int t = 0; t < LCHUNK; ++t) {
        float dtv = __bfloat162float(dpp[(size_t)t * D_INNER]);
        float du = dtv * __bfloat162float(upp[(size_t)t * D_INNER]);
        const float4* b4 = (const float4*)&Bsm[t][0];
        #pragma unroll
        for (int q = 0; q < 4; ++q) {
            float4 v = b4[q];
            float Bn[4] = {v.x, v.y, v.z, v.w};
            #pragma unroll
            for (int e = 0; e < 4; ++e) {
                int n = q * 4 + e;
                float a = __expf(dtv * A_row[n]);
                P[n] *= a;
                S[n] = fmaf(a, S[n], du * Bn[e]);
            }
        }
    }
    const size_t base = ((size_t)(b * NCHUNK + c) * D_STATE) * D_INNER + d;
    #pragma unroll
    for (int n = 0; n < D_STATE; ++n) {
        Pst[base + (size_t)n * D_INNER] = P[n];
        Sst[base + (size_t)n * D_INNER] = S[n];
    }
}

// Phase 2: combine chunk transforms; write h_in per chunk IN-PLACE over Sst.
// All loads address-independent: preload into regs, chain in-register.
__global__ __launch_bounds__(256)
void scan_phase2(const float* __restrict__ Pst, float* __restrict__ Sst)
{
    const int d = blockIdx.x * 256 + threadIdx.x;
    const int n = blockIdx.y;
    const int b = blockIdx.z;
    float Pv[NCHUNK], Sv[NCHUNK];
    #pragma unroll
    for (int c = 0; c < NCHUNK; ++c) {
        const size_t idx = ((size_t)(b * NCHUNK + c) * D_STATE + n) * D_INNER + d;
        Pv[c] = Pst[idx];
        Sv[c] = Sst[idx];
    }
    float h = 0.f;
    #pragma unroll
    for (int c = 0; c < NCHUNK; ++c) {
        float hin = h;
        h = fmaf(Pv[c], h, Sv[c]);
        Sv[c] = hin;                        // h_in for chunk c
    }
    #pragma unroll
    for (int c = 0; c < NCHUNK; ++c) {
        const size_t idx = ((size_t)(b * NCHUNK + c) * D_STATE + n) * D_INNER + d;
        Sst[idx] = Sv[c];
    }
}

__global__ __launch_bounds__(256)
void scan_phase3(const bf16* __restrict__ dt_sb,
                 const float* __restrict__ Aneg,
                 const bf16* __restrict__ u_bf,
                 const float* __restrict__ x_dbl,
                 const float* __restrict__ Dvec,
                 const bf16* __restrict__ sz_bf,  // silu(z), bf16
                 const float* __restrict__ hin,   // == Sst after phase2
                 bf16* __restrict__ g_bf)
{
    __shared__ float BCs[LCHUNK][32];
    const int d = blockIdx.x * 256 + threadIdx.x;
    const int c = blockIdx.y, b = blockIdx.z;
    const int t0 = c * LCHUNK;
    for (int i = threadIdx.x; i < LCHUNK * 32; i += 256) {   // stage B and C rows
        int tt = i >> 5, col = i & 31;
        BCs[tt][col] = x_dbl[(size_t)(b * SEQLEN + t0 + tt) * XCOLS + DT_RANK + col];
    }
    float A_row[D_STATE];
    const float4* a4 = (const float4*)(Aneg + d * D_STATE);
    #pragma unroll
    for (int q = 0; q < 4; ++q) {
        float4 v = a4[q];
        A_row[q*4+0] = v.x; A_row[q*4+1] = v.y; A_row[q*4+2] = v.z; A_row[q*4+3] = v.w;
    }
    const float Dd = Dvec[d];
    __syncthreads();
    float h[D_STATE];
    const size_t base = ((size_t)(b * NCHUNK + c) * D_STATE) * D_INNER + d;
    #pragma unroll
    for (int n = 0; n < D_STATE; ++n) h[n] = hin[base + (size_t)n * D_INNER];
    const bf16* dpp = dt_sb + (size_t)(b * SEQLEN + t0) * D_INNER + d;
    const bf16* upp = u_bf + (size_t)(b * SEQLEN + t0) * D_INNER + d;
    const bf16* zpp = sz_bf + (size_t)(b * SEQLEN + t0) * D_INNER + d;
    bf16* gpp = g_bf + (size_t)(b * SEQLEN + t0) * D_INNER + d;
    #pragma unroll 4
    for (int t = 0; t < LCHUNK; ++t) {
        float dtv = __bfloat162float(dpp[(size_t)t * D_INNER]);
        float uv = __bfloat162float(upp[(size_t)t * D_INNER]);
        float sz = __bfloat162float(zpp[(size_t)t * D_INNER]);
        float du = dtv * uv;
        float y = 0.f;
        const float4* bc4 = (const float4*)&BCs[t][0];
        #pragma unroll
        for (int q = 0; q < 4; ++q) {
            float4 v = bc4[q];
            float4 w = bc4[q + 4];
            float Bn[4] = {v.x, v.y, v.z, v.w};
            float Cn[4] = {w.x, w.y, w.z, w.w};
            #pragma unroll
            for (int e = 0; e < 4; ++e) {
                int n = q * 4 + e;
                float a = __expf(dtv * A_row[n]);
                h[n] = fmaf(a, h[n], du * Bn[e]);
                y = fmaf(h[n], Cn[e], y);
            }
        }
        float gy = y + uv * Dd;
        gpp[(size_t)t * D_INNER] = __float2bfloat16(gy * sz);
    }
}

extern "C" void kernel_launch(void* const* d_in, const int* in_sizes, int n_in,
                              void* d_out, int out_size, void* d_ws, size_t ws_size,
                              hipStream_t stream)
{
    const float* x      = (const float*)d_in[0];
    const float* W_in   = (const float*)d_in[1];
    const float* conv_k = (const float*)d_in[2];
    const float* conv_b = (const float*)d_in[3];
    const float* W_xproj= (const float*)d_in[4];
    const float* W_dt   = (const float*)d_in[5];
    const float* b_dt   = (const float*)d_in[6];
    const float* A_log  = (const float*)d_in[7];
    const float* Dvec   = (const float*)d_in[8];
    const float* W_out  = (const float*)d_in[9];
    float* out = (float*)d_out;

    const int BL = BATCH * SEQLEN;                    // 2048

    // fp32 region
    float* ws     = (float*)d_ws;
    float* x_dbl  = ws;                                 //   327,680
    float* Pst    = x_dbl + (size_t)BL * XCOLS;         // 2,097,152
    float* Sst    = Pst + (size_t)BATCH * NCHUNK * D_STATE * D_INNER;   // 2,097,152
    float* Aneg   = Sst + (size_t)BATCH * NCHUNK * D_STATE * D_INNER;   //    32,768
    float* Cpart  = Aneg + 32768;                       // 4,194,304 floats (GEMM3: 8x2048x256; GEMM6: 2x2048x1024)
    bf16*  x_bf   = (bf16*)Cpart;                       // 2048x1024, dead before GEMM3
    // bf16 region
    bf16* Win_t  = (bf16*)(Cpart + (size_t)4 * 1048576);// 4096 x 1024
    bf16* xd_bf  = Win_t + (size_t)4096 * 1024;         // 2048 x 2048 (x half, bf16)
    bf16* u_bf   = xd_bf + (size_t)BL * D_INNER;        // 2048 x 2048
    bf16* sz_bf  = u_bf  + (size_t)BL * D_INNER;        // 2048 x 2048 (silu(z))
    bf16* Wxp_t  = sz_bf + (size_t)BL * D_INNER;        // 256  x 2048 (padded)
    bf16* dtA_bf = Wxp_t + (size_t)256 * 2048;          // 2048 x 128
    bf16* Wdt_t  = dtA_bf+ (size_t)BL * DT_RANK;        // 2048 x 128
    bf16* g_bf   = Wdt_t + (size_t)2048 * 128;          // 2048 x 2048
    bf16* Wout_t = g_bf  + (size_t)BL * D_INNER;        // 1024 x 2048
    bf16* dt_sb  = Wout_t+ (size_t)1024 * 2048;         // 2048 x 2048

    // 0) fused prep: 4 transposes + x convert + Aneg
    prep_kernel<<<4096 + 512 + 256 + 2048 + 2048 + 128, 256, 0, stream>>>(
        x, x_bf, W_in, Win_t, W_xproj, Wxp_t, W_dt, Wdt_t, W_out, Wout_t, A_log, Aneg);

    // 1) in_proj: BN=64 -> 1024 blocks = 4 blocks/CU (16 waves/CU latency hiding)
    gemm_mfma<64, 2><<<dim3(64, 16, 1), 256, 0, stream>>>(
        x_bf, Win_t, nullptr, sz_bf, xd_bf, nullptr, BL, 2 * D_INNER, D_MODEL, D_INNER, D_MODEL);

    // 2) u_bf = bf16(silu(causal_conv(xd_bf) + b))
    conv_silu_kernel<<<(BL * D_INNER / 8) / 256, 256, 0, stream>>>(xd_bf, conv_k, conv_b, u_bf);

    // 3) x_dbl = u @ W_xproj  split-K 8, BN=64, 3 col-blocks (cols 0..191 cover 160)
    gemm_mfma<64, 0><<<dim3(3, 16, 8), 256, 0, stream>>>(
        u_bf, Wxp_t, Cpart, nullptr, nullptr, nullptr, BL, 256, D_INNER, 256, 256);
    reduce_xdbl<<<(BL * (XCOLS / 4) + 255) / 256, 256, 0, stream>>>(Cpart, x_dbl, dtA_bf);

    // 4) dt_sb = bf16(softplus(dt_low @ W_dt + b_dt)), BN=64 -> 512 blocks
    gemm_mfma<64, 1><<<dim3(32, 16, 1), 256, 0, stream>>>(
        dtA_bf, Wdt_t, nullptr, dt_sb, nullptr, b_dt, BL, D_INNER, DT_RANK, D_INNER, DT_RANK);

    // 5) chunked selective scan -> g_bf = bf16((y + u*D) * silu(z))
    scan_phase1<<<dim3(D_INNER / 256, NCHUNK, BATCH), 256, 0, stream>>>(
        dt_sb, Aneg, u_bf, x_dbl, Pst, Sst);
    scan_phase2<<<dim3(D_INNER / 256, D_STATE, BATCH), 256, 0, stream>>>(Pst, Sst);
    scan_phase3<<<dim3(D_INNER / 256, NCHUNK, BATCH), 256, 0, stream>>>(
        dt_sb, Aneg, u_bf, x_dbl, Dvec, sz_bf, Sst, g_bf);

    // 6) out = g @ W_out  split-K 2, BN=64 -> 512 blocks (R3 config, best measured)
    gemm_mfma<64, 0><<<dim3(16, 16, 2), 256, 0, stream>>>(
        g_bf, Wout_t, Cpart, nullptr, nullptr, nullptr, BL, D_MODEL, D_INNER, D_MODEL, D_INNER / 2);
    reduce_out<<<(BL * D_MODEL / 4) / 256, 256, 0, stream>>>(Cpart, out);
}

// Round 8
// 225.148 us; speedup vs baseline: 1.0475x; 1.0191x over previous
//
#include <hip/hip_runtime.h>
#include <hip/hip_bf16.h>

#define D_MODEL 1024
#define D_STATE 16
#define D_CONV 4
#define D_INNER 2048
#define DT_RANK 128
#define BATCH 2
#define SEQLEN 1024
#define XCOLS 160     // DT_RANK + 2*D_STATE
#define NCHUNK 32
#define LCHUNK 32     // SEQLEN / NCHUNK

typedef __hip_bfloat16 bf16;
typedef __attribute__((ext_vector_type(8))) short short8;
typedef __attribute__((ext_vector_type(4))) float f32x4;

__device__ __forceinline__ unsigned short f2bf_bits(float f) {
    bf16 h = __float2bfloat16(f);
    return *(unsigned short*)&h;
}

__device__ __forceinline__ float bfbits2f(short s) {
    union { float f; unsigned u; } v;
    v.u = ((unsigned)(unsigned short)s) << 16;
    return v.f;
}

__device__ __forceinline__ float softplus_f(float x) {
    return fmaxf(x, 0.f) + __logf(1.f + __expf(-fabsf(x)));
}

__device__ __forceinline__ float silu_f(float x) {
    return x / (1.f + __expf(-x));
}

// async global->LDS 16B per lane; LDS dest must be wave-uniform base + lane*16.
__device__ __forceinline__ void load16_lds(void* lds, const void* g) {
    __builtin_amdgcn_global_load_lds(
        (const __attribute__((address_space(1))) unsigned int*)g,
        (__attribute__((address_space(3))) unsigned int*)lds, 16, 0, 0);
}

// ---------------- fused prep: weight transposes + x convert + A precompute ----
__device__ __forceinline__ void transpose_tile(const float* __restrict__ B,
                                               bf16* __restrict__ Bt,
                                               int K, int N, int nt, int kt,
                                               float (*t)[33], int tid)
{
    const int tx = tid & 31, ty = tid >> 5;
    const int n0 = nt * 32, k0 = kt * 32;
    #pragma unroll
    for (int r = 0; r < 4; ++r) {
        int n = n0 + tx;
        t[ty + r * 8][tx] = (n < N) ? B[(size_t)(k0 + ty + r * 8) * N + n] : 0.f;
    }
    __syncthreads();
    #pragma unroll
    for (int r = 0; r < 4; ++r)
        Bt[(size_t)(n0 + ty + r * 8) * K + k0 + tx] = __float2bfloat16(t[tx][ty + r * 8]);
}

__global__ __launch_bounds__(256)
void prep_kernel(const float* __restrict__ x, bf16* __restrict__ x_bf,
                 const float* __restrict__ W_in, bf16* __restrict__ Win_t,
                 const float* __restrict__ W_xproj, bf16* __restrict__ Wxp_t,
                 const float* __restrict__ W_dt, bf16* __restrict__ Wdt_t,
                 const float* __restrict__ W_out, bf16* __restrict__ Wout_t,
                 const float* __restrict__ A_log, float* __restrict__ Aneg)
{
    __shared__ float t[32][33];
    const int tid = threadIdx.x;
    int blk = blockIdx.x;
    if (blk < 4096) {            // W_in: K=1024, Npad=4096 -> 128 x 32 tiles
        transpose_tile(W_in, Win_t, D_MODEL, 2 * D_INNER, blk & 127, blk >> 7, t, tid);
        return;
    }
    blk -= 4096;
    if (blk < 512) {             // W_xproj: K=2048, Npad=256 -> 8 x 64 tiles
        transpose_tile(W_xproj, Wxp_t, D_INNER, XCOLS, blk & 7, blk >> 3, t, tid);
        return;
    }
    blk -= 512;
    if (blk < 256) {             // W_dt: K=128, N=2048 -> 64 x 4 tiles
        transpose_tile(W_dt, Wdt_t, DT_RANK, D_INNER, blk & 63, blk >> 6, t, tid);
        return;
    }
    blk -= 256;
    if (blk < 2048) {            // W_out: K=2048, N=1024 -> 32 x 64 tiles
        transpose_tile(W_out, Wout_t, D_INNER, D_MODEL, blk & 31, blk >> 5, t, tid);
        return;
    }
    blk -= 2048;
    if (blk < 2048) {            // x -> bf16, float4
        int i = blk * 256 + tid;
        float4 v = ((const float4*)x)[i];
        ushort4 p;
        p.x = f2bf_bits(v.x); p.y = f2bf_bits(v.y);
        p.z = f2bf_bits(v.z); p.w = f2bf_bits(v.w);
        ((ushort4*)x_bf)[i] = p;
        return;
    }
    blk -= 2048;
    {                            // Aneg = -exp(A_log)
        int i = blk * 256 + tid;
        Aneg[i] = -__expf(A_log[i]);
    }
}

// ---------------- MFMA GEMM (tile 128xBN, BK=64, split-K capable) ------------
// 2-phase double-buffered pipeline (R3 schedule), BK=64: HALF the barrier-drain
// events of BK=32, 2x MFMA per drain. LDS swizzle sigma(row)=row&7 (involution
// on both stage-source chunk and ds_read chunk; 2-way banks = free).
// XCD-chunked bijective block remap.
// EPI=0: fp32 store to C. EPI=1: bf16 softplus(acc+bias) to Cb.
// EPI=2: cols [0,2048) -> bf16 to Cb2, cols [2048,4096) -> bf16 silu to Cb.
// Requires kchunk % 128 == 0 (call sites: 1024/256/128/1024).
template<int BN, int EPI>
__global__ __launch_bounds__(256)
void gemm_mfma(const bf16* __restrict__ A, const bf16* __restrict__ Bt,
               float* __restrict__ C, bf16* __restrict__ Cb,
               bf16* __restrict__ Cb2,
               const float* __restrict__ bias,
               int M, int N, int K, int ldc, int kchunk)
{
    constexpr int WN = (BN == 128) ? 64 : 32;
    constexpr int NJ = WN / 16;
    constexpr int BL_ = BN / 32;          // B stage loads: 128->4, 64->2
    __shared__ short As[2][128 * 64];     // 32 KB
    __shared__ short Bs[2][BN * 64];      // 32 KB (BN=128) / 16 KB (BN=64)
    const int tid = threadIdx.x;
    const int lane = tid & 63, wave = tid >> 6;
    const int wm = (wave >> 1) * 64, wn = (wave & 1) * WN;

    // XCD-chunked bijective remap (all our grids have total % 8 == 0).
    const int gx = gridDim.x, gy = gridDim.y;
    const int total = gx * gy * gridDim.z;
    const int hwid = (blockIdx.z * gy + blockIdx.y) * gx + blockIdx.x;
    const int nid = (hwid & 7) * (total >> 3) + (hwid >> 3);
    const int bz = nid / (gx * gy);
    const int rem = nid - bz * (gx * gy);
    const int bx = rem / gy;
    const int by = rem - bx * gy;

    const int row0 = by * 128, col0 = bx * BN;
    const int r_m = lane & 15, r_q = lane >> 4;
    const int kstart = bz * kchunk;
    float* Cz = C + (size_t)bz * M * ldc;

    // staging: load L of a buffer covers LDS rows [L*32, L*32+32); thread t
    // -> row L*32 + (t>>3), col-chunk (t&7). Source chunk XOR-swizzled:
    // LDS[row][c] = G[row][c ^ (row&7)]; (L*32+(t>>3))&7 == (t>>3)&7.
    const int srow = tid >> 3;            // 0..31
    const int schk = ((tid & 7) ^ (srow & 7)) * 8;
    const bf16* Ag = A  + (size_t)(row0 + srow) * K + kstart + schk;
    const bf16* Bg = Bt + (size_t)(col0 + srow) * K + kstart + schk;

    f32x4 acc[4][NJ];
    #pragma unroll
    for (int i = 0; i < 4; ++i)
        #pragma unroll
        for (int j = 0; j < NJ; ++j)
            #pragma unroll
            for (int r = 0; r < 4; ++r) acc[i][j][r] = 0.f;

#define GEMM_STAGE(BUF, KOFF)                                                   \
    {                                                                           \
        _Pragma("unroll")                                                       \
        for (int L = 0; L < 4; ++L)                                             \
            load16_lds(&As[BUF][2048 * L + 8 * tid],                            \
                       Ag + (size_t)(L * 32) * K + (KOFF));                     \
        _Pragma("unroll")                                                       \
        for (int L = 0; L < BL_; ++L)                                           \
            load16_lds(&Bs[BUF][2048 * L + 8 * tid],                            \
                       Bg + (size_t)(L * 32) * K + (KOFF));                     \
    }

    // read chunk for MFMA k-subtile kk (k = kk*32 + r_q*8): chunk q = kk*4+r_q,
    // swizzled with row&7 == r_m&7.
#define GEMM_COMPUTE(BUF)                                                       \
    {                                                                           \
        short8 af[2][4], bfr[2][NJ];                                            \
        _Pragma("unroll")                                                       \
        for (int kk = 0; kk < 2; ++kk) {                                        \
            const int cxk = ((kk * 4 + r_q) ^ (r_m & 7)) * 8;                   \
            _Pragma("unroll")                                                   \
            for (int i = 0; i < 4; ++i)                                         \
                af[kk][i] = *(const short8*)&As[BUF][(wm + i * 16 + r_m) * 64 + cxk]; \
            _Pragma("unroll")                                                   \
            for (int j = 0; j < NJ; ++j)                                        \
                bfr[kk][j] = *(const short8*)&Bs[BUF][(wn + j * 16 + r_m) * 64 + cxk]; \
        }                                                                       \
        _Pragma("unroll")                                                       \
        for (int kk = 0; kk < 2; ++kk)                                          \
            _Pragma("unroll")                                                   \
            for (int i = 0; i < 4; ++i)                                         \
                _Pragma("unroll")                                               \
                for (int j = 0; j < NJ; ++j)                                    \
                    acc[i][j] = __builtin_amdgcn_mfma_f32_16x16x32_bf16(        \
                        af[kk][i], bfr[kk][j], acc[i][j], 0, 0, 0);             \
    }

    // prologue
    GEMM_STAGE(0, 0);
    __syncthreads();                     // vmcnt drained -> buf0 visible
    for (int k0 = 0; k0 < kchunk; k0 += 128) {
        GEMM_STAGE(1, k0 + 64);          // prefetch overlaps compute(0)
        GEMM_COMPUTE(0);
        __syncthreads();                 // drains vmcnt -> buf1 visible; buf0 reads done
        if (k0 + 128 < kchunk) GEMM_STAGE(0, k0 + 128);
        GEMM_COMPUTE(1);
        __syncthreads();
    }
#undef GEMM_STAGE
#undef GEMM_COMPUTE

    #pragma unroll
    for (int i = 0; i < 4; ++i) {
        #pragma unroll
        for (int j = 0; j < NJ; ++j) {
            int row = row0 + wm + i * 16 + r_q * 4;
            int col = col0 + wn + j * 16 + r_m;
            if (col < N) {
                if (EPI == 1) {
                    float bv = bias[col];
                    #pragma unroll
                    for (int r = 0; r < 4; ++r)
                        Cb[(size_t)(row + r) * ldc + col] =
                            __float2bfloat16(softplus_f(acc[i][j][r] + bv));
                } else if (EPI == 2) {
                    if (col < 2048) {        // x half -> bf16 (conv input)
                        #pragma unroll
                        for (int r = 0; r < 4; ++r)
                            Cb2[(size_t)(row + r) * ldc + col] =
                                __float2bfloat16(acc[i][j][r]);
                    } else {                 // z half -> bf16 silu(z)
                        int zc = col - 2048;
                        #pragma unroll
                        for (int r = 0; r < 4; ++r)
                            Cb[(size_t)(row + r) * ldc + zc] =
                                __float2bfloat16(silu_f(acc[i][j][r]));
                    }
                } else {
                    #pragma unroll
                    for (int r = 0; r < 4; ++r)
                        Cz[(size_t)(row + r) * ldc + col] = acc[i][j][r];
                }
            }
        }
    }
}

// reduce 8 split-K partials (ldc=256) -> x_dbl fp32 (160 cols) + dt_low bf16
__global__ __launch_bounds__(256)
void reduce_xdbl(const float* __restrict__ Cpart, float* __restrict__ x_dbl,
                 bf16* __restrict__ dtA_bf)
{
    int i4 = blockIdx.x * 256 + threadIdx.x;         // 2048 * 40 float4-groups
    if (i4 >= 2048 * (XCOLS / 4)) return;
    int r = i4 / (XCOLS / 4), c4 = i4 - r * (XCOLS / 4);
    float4 s = {0.f, 0.f, 0.f, 0.f};
    #pragma unroll
    for (int z = 0; z < 8; ++z) {
        float4 v = *(const float4*)&Cpart[(size_t)z * 2048 * 256 + (size_t)r * 256 + c4 * 4];
        s.x += v.x; s.y += v.y; s.z += v.z; s.w += v.w;
    }
    *(float4*)&x_dbl[(size_t)r * XCOLS + c4 * 4] = s;
    if (c4 < DT_RANK / 4) {
        ushort4 p;
        p.x = f2bf_bits(s.x); p.y = f2bf_bits(s.y);
        p.z = f2bf_bits(s.z); p.w = f2bf_bits(s.w);
        *(ushort4*)&dtA_bf[(size_t)r * DT_RANK + c4 * 4] = p;
    }
}

// reduce 2 split-K partials -> out fp32, float4
__global__ __launch_bounds__(256)
void reduce_out(const float* __restrict__ Cpart, float* __restrict__ out)
{
    int i = blockIdx.x * 256 + threadIdx.x;          // (2048*1024)/4
    const float4* p0 = (const float4*)Cpart;
    const float4* p1 = p0 + (size_t)2048 * 1024 / 4;
    float4 a = p0[i], b = p1[i];
    float4 r; r.x = a.x + b.x; r.y = a.y + b.y; r.z = a.z + b.z; r.w = a.w + b.w;
    ((float4*)out)[i] = r;
}

// ---------------- conv + silu (short8 over d), bf16 in / bf16 out ------------
// xd is dense [B*L][D_INNER] bf16 (the x half of in_proj).
__global__ __launch_bounds__(256)
void conv_silu_kernel(const bf16* __restrict__ xd,
                      const float* __restrict__ conv_k,
                      const float* __restrict__ conv_b,
                      bf16* __restrict__ u_bf)
{
    int idx8 = blockIdx.x * 256 + threadIdx.x;       // B*L*Di/8 = 524288
    int d8 = idx8 & (D_INNER / 8 - 1);
    int t = (idx8 >> 8) & (SEQLEN - 1);
    int b = idx8 >> 18;
    float acc[8];
    {
        float4 b0 = ((const float4*)conv_b)[d8 * 2];
        float4 b1 = ((const float4*)conv_b)[d8 * 2 + 1];
        acc[0] = b0.x; acc[1] = b0.y; acc[2] = b0.z; acc[3] = b0.w;
        acc[4] = b1.x; acc[5] = b1.y; acc[6] = b1.z; acc[7] = b1.w;
    }
    #pragma unroll
    for (int k = 0; k < D_CONV; ++k) {
        int tt = t + k - (D_CONV - 1);
        if (tt >= 0) {
            short8 xv = ((const short8*)xd)[(size_t)(b * SEQLEN + tt) * (D_INNER / 8) + d8];
            float4 k0 = ((const float4*)conv_k)[k * (D_INNER / 4) + d8 * 2];
            float4 k1 = ((const float4*)conv_k)[k * (D_INNER / 4) + d8 * 2 + 1];
            acc[0] = fmaf(bfbits2f(xv[0]), k0.x, acc[0]);
            acc[1] = fmaf(bfbits2f(xv[1]), k0.y, acc[1]);
            acc[2] = fmaf(bfbits2f(xv[2]), k0.z, acc[2]);
            acc[3] = fmaf(bfbits2f(xv[3]), k0.w, acc[3]);
            acc[4] = fmaf(bfbits2f(xv[4]), k1.x, acc[4]);
            acc[5] = fmaf(bfbits2f(xv[5]), k1.y, acc[5]);
            acc[6] = fmaf(bfbits2f(xv[6]), k1.z, acc[6]);
            acc[7] = fmaf(bfbits2f(xv[7]), k1.w, acc[7]);
        }
    }
    short8 r;
    #pragma unroll
    for (int j = 0; j < 8; ++j)
        r[j] = (short)f2bf_bits(acc[j] / (1.f + __expf(-acc[j])));
    ((short8*)u_bf)[idx8] = r;
}

// ---------------- chunked scan ----------------
// dt_sb = bf16 softplus(dt_pre + b_dt) (GEMM4 epilogue).
__global__ __launch_bounds__(256)
void scan_phase1(const bf16* __restrict__ dt_sb,
                 const float* __restrict__ Aneg,
                 const bf16* __restrict__ u_bf,
                 const float* __restrict__ x_dbl,
                 float* __restrict__ Pst, float* __restrict__ Sst)
{
    __shared__ float Bsm[LCHUNK][16];
    const int d = blockIdx.x * 256 + threadIdx.x;
    const int c = blockIdx.y, b = blockIdx.z;
    const int t0 = c * LCHUNK;
    for (int i = threadIdx.x; i < LCHUNK * 16; i += 256) {   // stage B rows
        int tt = i >> 4, n = i & 15;
        Bsm[tt][n] = x_dbl[(size_t)(b * SEQLEN + t0 + tt) * XCOLS + DT_RANK + n];
    }
    float A_row[D_STATE];
    const float4* a4 = (const float4*)(Aneg + d * D_STATE);
    #pragma unroll
    for (int q = 0; q < 4; ++q) {
        float4 v = a4[q];
        A_row[q*4+0] = v.x; A_row[q*4+1] = v.y; A_row[q*4+2] = v.z; A_row[q*4+3] = v.w;
    }
    __syncthreads();
    float P[D_STATE], S[D_STATE];
    #pragma unroll
    for (int n = 0; n < D_STATE; ++n) { P[n] = 1.f; S[n] = 0.f; }
    const bf16* dpp = dt_sb + (size_t)(b * SEQLEN + t0) * D_INNER + d;
    const bf16* upp = u_bf + (size_t)(b * SEQLEN + t0) * D_INNER + d;
    #pragma unroll 4
    for (int t = 0; t < LCHUNK; ++t) {
        float dtv = __bfloat162float(dpp[(size_t)t * D_INNER]);
        float du = dtv * __bfloat162float(upp[(size_t)t * D_INNER]);
        const float4* b4 = (const float4*)&Bsm[t][0];
        #pragma unroll
        for (int q = 0; q < 4; ++q) {
            float4 v = b4[q];
            float Bn[4] = {v.x, v.y, v.z, v.w};
            #pragma unroll
            for (int e = 0; e < 4; ++e) {
                int n = q * 4 + e;
                float a = __expf(dtv * A_row[n]);
                P[n] *= a;
                S[n] = fmaf(a, S[n], du * Bn[e]);
            }
        }
    }
    const size_t base = ((size_t)(b * NCHUNK + c) * D_STATE) * D_INNER + d;
    #pragma unroll
    for (int n = 0; n < D_STATE; ++n) {
        Pst[base + (size_t)n * D_INNER] = P[n];
        Sst[base + (size_t)n * D_INNER] = S[n];
    }
}

// Phase 2: combine chunk transforms; write h_in per chunk IN-PLACE over Sst.
// All loads address-independent: preload into regs, chain in-register.
__global__ __launch_bounds__(256)
void scan_phase2(const float* __restrict__ Pst, float* __restrict__ Sst)
{
    const int d = blockIdx.x * 256 + threadIdx.x;
    const int n = blockIdx.y;
    const int b = blockIdx.z;
    float Pv[NCHUNK], Sv[NCHUNK];
    #pragma unroll
    for (int c = 0; c < NCHUNK; ++c) {
        const size_t idx = ((size_t)(b * NCHUNK + c) * D_STATE + n) * D_INNER + d;
        Pv[c] = Pst[idx];
        Sv[c] = Sst[idx];
    }
    float h = 0.f;
    #pragma unroll
    for (int c = 0; c < NCHUNK; ++c) {
        float hin = h;
        h = fmaf(Pv[c], h, Sv[c]);
        Sv[c] = hin;                        // h_in for chunk c
    }
    #pragma unroll
    for (int c = 0; c < NCHUNK; ++c) {
        const size_t idx = ((size_t)(b * NCHUNK + c) * D_STATE + n) * D_INNER + d;
        Sst[idx] = Sv[c];
    }
}

__global__ __launch_bounds__(256)
void scan_phase3(const bf16* __restrict__ dt_sb,
                 const float* __restrict__ Aneg,
                 const bf16* __restrict__ u_bf,
                 const float* __restrict__ x_dbl,
                 const float* __restrict__ Dvec,
                 const bf16* __restrict__ sz_bf,  // silu(z), bf16
                 const float* __restrict__ hin,   // == Sst after phase2
                 bf16* __restrict__ g_bf)
{
    __shared__ float BCs[LCHUNK][32];
    const int d = blockIdx.x * 256 + threadIdx.x;
    const int c = blockIdx.y, b = blockIdx.z;
    const int t0 = c * LCHUNK;
    for (int i = threadIdx.x; i < LCHUNK * 32; i += 256) {   // stage B and C rows
        int tt = i >> 5, col = i & 31;
        BCs[tt][col] = x_dbl[(size_t)(b * SEQLEN + t0 + tt) * XCOLS + DT_RANK + col];
    }
    float A_row[D_STATE];
    const float4* a4 = (const float4*)(Aneg + d * D_STATE);
    #pragma unroll
    for (int q = 0; q < 4; ++q) {
        float4 v = a4[q];
        A_row[q*4+0] = v.x; A_row[q*4+1] = v.y; A_row[q*4+2] = v.z; A_row[q*4+3] = v.w;
    }
    const float Dd = Dvec[d];
    __syncthreads();
    float h[D_STATE];
    const size_t base = ((size_t)(b * NCHUNK + c) * D_STATE) * D_INNER + d;
    #pragma unroll
    for (int n = 0; n < D_STATE; ++n) h[n] = hin[base + (size_t)n * D_INNER];
    const bf16* dpp = dt_sb + (size_t)(b * SEQLEN + t0) * D_INNER + d;
    const bf16* upp = u_bf + (size_t)(b * SEQLEN + t0) * D_INNER + d;
    const bf16* zpp = sz_bf + (size_t)(b * SEQLEN + t0) * D_INNER + d;
    bf16* gpp = g_bf + (size_t)(b * SEQLEN + t0) * D_INNER + d;
    #pragma unroll 4
    for (int t = 0; t < LCHUNK; ++t) {
        float dtv = __bfloat162float(dpp[(size_t)t * D_INNER]);
        float uv = __bfloat162float(upp[(size_t)t * D_INNER]);
        float sz = __bfloat162float(zpp[(size_t)t * D_INNER]);
        float du = dtv * uv;
        float y = 0.f;
        const float4* bc4 = (const float4*)&BCs[t][0];
        #pragma unroll
        for (int q = 0; q < 4; ++q) {
            float4 v = bc4[q];
            float4 w = bc4[q + 4];
            float Bn[4] = {v.x, v.y, v.z, v.w};
            float Cn[4] = {w.x, w.y, w.z, w.w};
            #pragma unroll
            for (int e = 0; e < 4; ++e) {
                int n = q * 4 + e;
                float a = __expf(dtv * A_row[n]);
                h[n] = fmaf(a, h[n], du * Bn[e]);
                y = fmaf(h[n], Cn[e], y);
            }
        }
        float gy = y + uv * Dd;
        gpp[(size_t)t * D_INNER] = __float2bfloat16(gy * sz);
    }
}

extern "C" void kernel_launch(void* const* d_in, const int* in_sizes, int n_in,
                              void* d_out, int out_size, void* d_ws, size_t ws_size,
                              hipStream_t stream)
{
    const float* x      = (const float*)d_in[0];
    const float* W_in   = (const float*)d_in[1];
    const float* conv_k = (const float*)d_in[2];
    const float* conv_b = (const float*)d_in[3];
    const float* W_xproj= (const float*)d_in[4];
    const float* W_dt   = (const float*)d_in[5];
    const float* b_dt   = (const float*)d_in[6];
    const float* A_log  = (const float*)d_in[7];
    const float* Dvec   = (const float*)d_in[8];
    const float* W_out  = (const float*)d_in[9];
    float* out = (float*)d_out;

    const int BL = BATCH * SEQLEN;                    // 2048

    // fp32 region
    float* ws     = (float*)d_ws;
    float* x_dbl  = ws;                                 //   327,680
    float* Pst    = x_dbl + (size_t)BL * XCOLS;         // 2,097,152
    float* Sst    = Pst + (size_t)BATCH * NCHUNK * D_STATE * D_INNER;   // 2,097,152
    float* Aneg   = Sst + (size_t)BATCH * NCHUNK * D_STATE * D_INNER;   //    32,768
    float* Cpart  = Aneg + 32768;                       // 4,194,304 floats (GEMM3: 8x2048x256; GEMM6: 2x2048x1024)
    bf16*  x_bf   = (bf16*)Cpart;                       // 2048x1024, dead before GEMM3
    // bf16 region
    bf16* Win_t  = (bf16*)(Cpart + (size_t)4 * 1048576);// 4096 x 1024
    bf16* xd_bf  = Win_t + (size_t)4096 * 1024;         // 2048 x 2048 (x half, bf16)
    bf16* u_bf   = xd_bf + (size_t)BL * D_INNER;        // 2048 x 2048
    bf16* sz_bf  = u_bf  + (size_t)BL * D_INNER;        // 2048 x 2048 (silu(z))
    bf16* Wxp_t  = sz_bf + (size_t)BL * D_INNER;        // 256  x 2048 (padded)
    bf16* dtA_bf = Wxp_t + (size_t)256 * 2048;          // 2048 x 128
    bf16* Wdt_t  = dtA_bf+ (size_t)BL * DT_RANK;        // 2048 x 128
    bf16* g_bf   = Wdt_t + (size_t)2048 * 128;          // 2048 x 2048
    bf16* Wout_t = g_bf  + (size_t)BL * D_INNER;        // 1024 x 2048
    bf16* dt_sb  = Wout_t+ (size_t)1024 * 2048;         // 2048 x 2048

    // 0) fused prep: 4 transposes + x convert + Aneg
    prep_kernel<<<4096 + 512 + 256 + 2048 + 2048 + 128, 256, 0, stream>>>(
        x, x_bf, W_in, Win_t, W_xproj, Wxp_t, W_dt, Wdt_t, W_out, Wout_t, A_log, Aneg);

    // 1) in_proj: BN=128/BK=64 -> 512 blocks = 2/CU (64 KB LDS fits exactly)
    gemm_mfma<128, 2><<<dim3(32, 16, 1), 256, 0, stream>>>(
        x_bf, Win_t, nullptr, sz_bf, xd_bf, nullptr, BL, 2 * D_INNER, D_MODEL, D_INNER, D_MODEL);

    // 2) u_bf = bf16(silu(causal_conv(xd_bf) + b))
    conv_silu_kernel<<<(BL * D_INNER / 8) / 256, 256, 0, stream>>>(xd_bf, conv_k, conv_b, u_bf);

    // 3) x_dbl = u @ W_xproj  split-K 8, BN=64, 3 col-blocks (cols 0..191 cover 160)
    gemm_mfma<64, 0><<<dim3(3, 16, 8), 256, 0, stream>>>(
        u_bf, Wxp_t, Cpart, nullptr, nullptr, nullptr, BL, 256, D_INNER, 256, 256);
    reduce_xdbl<<<(BL * (XCOLS / 4) + 255) / 256, 256, 0, stream>>>(Cpart, x_dbl, dtA_bf);

    // 4) dt_sb = bf16(softplus(dt_low @ W_dt + b_dt)), BN=64 -> 512 blocks
    gemm_mfma<64, 1><<<dim3(32, 16, 1), 256, 0, stream>>>(
        dtA_bf, Wdt_t, nullptr, dt_sb, nullptr, b_dt, BL, D_INNER, DT_RANK, D_INNER, DT_RANK);

    // 5) chunked selective scan -> g_bf = bf16((y + u*D) * silu(z))
    scan_phase1<<<dim3(D_INNER / 256, NCHUNK, BATCH), 256, 0, stream>>>(
        dt_sb, Aneg, u_bf, x_dbl, Pst, Sst);
    scan_phase2<<<dim3(D_INNER / 256, D_STATE, BATCH), 256, 0, stream>>>(Pst, Sst);
    scan_phase3<<<dim3(D_INNER / 256, NCHUNK, BATCH), 256, 0, stream>>>(
        dt_sb, Aneg, u_bf, x_dbl, Dvec, sz_bf, Sst, g_bf);

    // 6) out = g @ W_out  split-K 2, BN=64 -> 512 blocks
    gemm_mfma<64, 0><<<dim3(16, 16, 2), 256, 0, stream>>>(
        g_bf, Wout_t, Cpart, nullptr, nullptr, nullptr, BL, D_MODEL, D_INNER, D_MODEL, D_INNER / 2);
    reduce_out<<<(BL * D_MODEL / 4) / 256, 256, 0, stream>>>(Cpart, out);
}

// Round 9
// 214.529 us; speedup vs baseline: 1.0993x; 1.0495x over previous
//
#include <hip/hip_runtime.h>
#include <hip/hip_bf16.h>

#define D_MODEL 1024
#define D_STATE 16
#define D_CONV 4
#define D_INNER 2048
#define DT_RANK 128
#define BATCH 2
#define SEQLEN 1024
#define XCOLS 160     // DT_RANK + 2*D_STATE
#define NCHUNK 32
#define LCHUNK 32     // SEQLEN / NCHUNK

typedef __hip_bfloat16 bf16;
typedef __attribute__((ext_vector_type(8))) short short8;
typedef __attribute__((ext_vector_type(4))) float f32x4;

__device__ __forceinline__ unsigned short f2bf_bits(float f) {
    bf16 h = __float2bfloat16(f);
    return *(unsigned short*)&h;
}

__device__ __forceinline__ float bfbits2f(short s) {
    union { float f; unsigned u; } v;
    v.u = ((unsigned)(unsigned short)s) << 16;
    return v.f;
}

__device__ __forceinline__ float softplus_f(float x) {
    return fmaxf(x, 0.f) + __logf(1.f + __expf(-fabsf(x)));
}

__device__ __forceinline__ float silu_f(float x) {
    return x / (1.f + __expf(-x));
}

// async global->LDS 16B per lane; LDS dest must be wave-uniform base + lane*16.
__device__ __forceinline__ void load16_lds(void* lds, const void* g) {
    __builtin_amdgcn_global_load_lds(
        (const __attribute__((address_space(1))) unsigned int*)g,
        (__attribute__((address_space(3))) unsigned int*)lds, 16, 0, 0);
}

// ---------------- fused prep: weight transposes + x convert + A precompute ----
__device__ __forceinline__ void transpose_tile(const float* __restrict__ B,
                                               bf16* __restrict__ Bt,
                                               int K, int N, int nt, int kt,
                                               float (*t)[33], int tid)
{
    const int tx = tid & 31, ty = tid >> 5;
    const int n0 = nt * 32, k0 = kt * 32;
    #pragma unroll
    for (int r = 0; r < 4; ++r) {
        int n = n0 + tx;
        t[ty + r * 8][tx] = (n < N) ? B[(size_t)(k0 + ty + r * 8) * N + n] : 0.f;
    }
    __syncthreads();
    #pragma unroll
    for (int r = 0; r < 4; ++r)
        Bt[(size_t)(n0 + ty + r * 8) * K + k0 + tx] = __float2bfloat16(t[tx][ty + r * 8]);
}

__global__ __launch_bounds__(256)
void prep_kernel(const float* __restrict__ x, bf16* __restrict__ x_bf,
                 const float* __restrict__ W_in, bf16* __restrict__ Win_t,
                 const float* __restrict__ W_xproj, bf16* __restrict__ Wxp_t,
                 const float* __restrict__ W_dt, bf16* __restrict__ Wdt_t,
                 const float* __restrict__ W_out, bf16* __restrict__ Wout_t,
                 const float* __restrict__ A_log, float* __restrict__ Aneg)
{
    __shared__ float t[32][33];
    const int tid = threadIdx.x;
    int blk = blockIdx.x;
    if (blk < 4096) {            // W_in: K=1024, Npad=4096 -> 128 x 32 tiles
        transpose_tile(W_in, Win_t, D_MODEL, 2 * D_INNER, blk & 127, blk >> 7, t, tid);
        return;
    }
    blk -= 4096;
    if (blk < 512) {             // W_xproj: K=2048, Npad=256 -> 8 x 64 tiles
        transpose_tile(W_xproj, Wxp_t, D_INNER, XCOLS, blk & 7, blk >> 3, t, tid);
        return;
    }
    blk -= 512;
    if (blk < 256) {             // W_dt: K=128, N=2048 -> 64 x 4 tiles
        transpose_tile(W_dt, Wdt_t, DT_RANK, D_INNER, blk & 63, blk >> 6, t, tid);
        return;
    }
    blk -= 256;
    if (blk < 2048) {            // W_out: K=2048, N=1024 -> 32 x 64 tiles
        transpose_tile(W_out, Wout_t, D_INNER, D_MODEL, blk & 31, blk >> 5, t, tid);
        return;
    }
    blk -= 2048;
    if (blk < 2048) {            // x -> bf16, float4
        int i = blk * 256 + tid;
        float4 v = ((const float4*)x)[i];
        ushort4 p;
        p.x = f2bf_bits(v.x); p.y = f2bf_bits(v.y);
        p.z = f2bf_bits(v.z); p.w = f2bf_bits(v.w);
        ((ushort4*)x_bf)[i] = p;
        return;
    }
    blk -= 2048;
    {                            // Aneg = -exp(A_log)
        int i = blk * 256 + tid;
        Aneg[i] = -__expf(A_log[i]);
    }
}

// ---------------- MFMA GEMM (tile 128xBN, BK=64, 512 threads / 8 waves) -----
// 2-phase double-buffered pipeline (R3 schedule, BK=64 from R8 — both proven).
// NEW: 8-wave blocks -> 4 waves/SIMD (BN=128, 2 blk/CU) or 6 (BN=64, 3 blk/CU)
// for latency hiding; no grid tail (512-block grids at 2/CU exact).
// Wave mapping: BN=128: 2M x 4N, per-wave 64x32 (acc[4][2]).
//               BN=64 : 4M x 2N, per-wave 32x32 (acc[2][2]).
// LDS swizzle sigma(row)=row&7 (involution both sides; 2-way banks = free).
// XCD-chunked bijective block remap.
// EPI=0: fp32 store to C. EPI=1: bf16 softplus(acc+bias) to Cb.
// EPI=2: cols [0,2048) -> bf16 to Cb2, cols [2048,4096) -> bf16 silu to Cb.
// Requires kchunk % 128 == 0 (call sites: 1024/256/128/1024).
template<int BN, int EPI>
__global__ __launch_bounds__(512)
void gemm_mfma(const bf16* __restrict__ A, const bf16* __restrict__ Bt,
               float* __restrict__ C, bf16* __restrict__ Cb,
               bf16* __restrict__ Cb2,
               const float* __restrict__ bias,
               int M, int N, int K, int ldc, int kchunk)
{
    constexpr int MI = (BN == 128) ? 4 : 2;   // A frags per wave
    constexpr int NJ = 2;                     // B frags per wave
    constexpr int BLB = BN / 64;              // B stage loads: 128->2, 64->1
    __shared__ short As[2][128 * 64];         // 32 KB
    __shared__ short Bs[2][BN * 64];          // 32 KB (BN=128) / 16 KB (BN=64)
    const int tid = threadIdx.x;
    const int lane = tid & 63, wave = tid >> 6;      // 8 waves
    // BN=128: wm=(wave>>2)*64, wn=(wave&3)*32.  BN=64: wm=(wave&3)*32, wn=(wave>>2)*32.
    const int wm = (BN == 128) ? (wave >> 2) * 64 : (wave & 3) * 32;
    const int wn = (BN == 128) ? (wave & 3) * 32 : (wave >> 2) * 32;

    // XCD-chunked bijective remap (all our grids have total % 8 == 0).
    const int gx = gridDim.x, gy = gridDim.y;
    const int total = gx * gy * gridDim.z;
    const int hwid = (blockIdx.z * gy + blockIdx.y) * gx + blockIdx.x;
    const int nid = (hwid & 7) * (total >> 3) + (hwid >> 3);
    const int bz = nid / (gx * gy);
    const int rem = nid - bz * (gx * gy);
    const int bx = rem / gy;
    const int by = rem - bx * gy;

    const int row0 = by * 128, col0 = bx * BN;
    const int r_m = lane & 15, r_q = lane >> 4;
    const int kstart = bz * kchunk;
    float* Cz = C + (size_t)bz * M * ldc;

    // staging: 512 threads x 16B = 8 KB = 64 rows per load call.
    // thread t -> row (t>>3), col-chunk (t&7); LDS[row][c] = G[row][c ^ (row&7)].
    const int srow = tid >> 3;            // 0..63
    const int schk = ((tid & 7) ^ (srow & 7)) * 8;
    const bf16* Ag = A  + (size_t)(row0 + srow) * K + kstart + schk;
    const bf16* Bg = Bt + (size_t)(col0 + srow) * K + kstart + schk;

    f32x4 acc[MI][NJ];
    #pragma unroll
    for (int i = 0; i < MI; ++i)
        #pragma unroll
        for (int j = 0; j < NJ; ++j)
            #pragma unroll
            for (int r = 0; r < 4; ++r) acc[i][j][r] = 0.f;

#define GEMM_STAGE(BUF, KOFF)                                                   \
    {                                                                           \
        _Pragma("unroll")                                                       \
        for (int L = 0; L < 2; ++L)                                             \
            load16_lds(&As[BUF][4096 * L + 8 * tid],                            \
                       Ag + (size_t)(L * 64) * K + (KOFF));                     \
        _Pragma("unroll")                                                       \
        for (int L = 0; L < BLB; ++L)                                           \
            load16_lds(&Bs[BUF][4096 * L + 8 * tid],                            \
                       Bg + (size_t)(L * 64) * K + (KOFF));                     \
    }

    // read chunk for MFMA k-subtile kk (k = kk*32 + r_q*8): chunk q = kk*4+r_q,
    // swizzled with row&7 == r_m&7 (wm, 16 are multiples of 8... wm%8==0).
#define GEMM_COMPUTE(BUF)                                                       \
    {                                                                           \
        short8 af[2][MI], bfr[2][NJ];                                           \
        _Pragma("unroll")                                                       \
        for (int kk = 0; kk < 2; ++kk) {                                        \
            const int cxk = ((kk * 4 + r_q) ^ (r_m & 7)) * 8;                   \
            _Pragma("unroll")                                                   \
            for (int i = 0; i < MI; ++i)                                        \
                af[kk][i] = *(const short8*)&As[BUF][(wm + i * 16 + r_m) * 64 + cxk]; \
            _Pragma("unroll")                                                   \
            for (int j = 0; j < NJ; ++j)                                        \
                bfr[kk][j] = *(const short8*)&Bs[BUF][(wn + j * 16 + r_m) * 64 + cxk]; \
        }                                                                       \
        _Pragma("unroll")                                                       \
        for (int kk = 0; kk < 2; ++kk)                                          \
            _Pragma("unroll")                                                   \
            for (int i = 0; i < MI; ++i)                                        \
                _Pragma("unroll")                                               \
                for (int j = 0; j < NJ; ++j)                                    \
                    acc[i][j] = __builtin_amdgcn_mfma_f32_16x16x32_bf16(        \
                        af[kk][i], bfr[kk][j], acc[i][j], 0, 0, 0);             \
    }

    // prologue
    GEMM_STAGE(0, 0);
    __syncthreads();                     // vmcnt drained -> buf0 visible
    for (int k0 = 0; k0 < kchunk; k0 += 128) {
        GEMM_STAGE(1, k0 + 64);          // prefetch overlaps compute(0)
        GEMM_COMPUTE(0);
        __syncthreads();                 // drains vmcnt -> buf1 visible; buf0 reads done
        if (k0 + 128 < kchunk) GEMM_STAGE(0, k0 + 128);
        GEMM_COMPUTE(1);
        __syncthreads();
    }
#undef GEMM_STAGE
#undef GEMM_COMPUTE

    #pragma unroll
    for (int i = 0; i < MI; ++i) {
        #pragma unroll
        for (int j = 0; j < NJ; ++j) {
            int row = row0 + wm + i * 16 + r_q * 4;
            int col = col0 + wn + j * 16 + r_m;
            if (col < N) {
                if (EPI == 1) {
                    float bv = bias[col];
                    #pragma unroll
                    for (int r = 0; r < 4; ++r)
                        Cb[(size_t)(row + r) * ldc + col] =
                            __float2bfloat16(softplus_f(acc[i][j][r] + bv));
                } else if (EPI == 2) {
                    if (col < 2048) {        // x half -> bf16 (conv input)
                        #pragma unroll
                        for (int r = 0; r < 4; ++r)
                            Cb2[(size_t)(row + r) * ldc + col] =
                                __float2bfloat16(acc[i][j][r]);
                    } else {                 // z half -> bf16 silu(z)
                        int zc = col - 2048;
                        #pragma unroll
                        for (int r = 0; r < 4; ++r)
                            Cb[(size_t)(row + r) * ldc + zc] =
                                __float2bfloat16(silu_f(acc[i][j][r]));
                    }
                } else {
                    #pragma unroll
                    for (int r = 0; r < 4; ++r)
                        Cz[(size_t)(row + r) * ldc + col] = acc[i][j][r];
                }
            }
        }
    }
}

// reduce 8 split-K partials (ldc=256) -> x_dbl fp32 (160 cols) + dt_low bf16
__global__ __launch_bounds__(256)
void reduce_xdbl(const float* __restrict__ Cpart, float* __restrict__ x_dbl,
                 bf16* __restrict__ dtA_bf)
{
    int i4 = blockIdx.x * 256 + threadIdx.x;         // 2048 * 40 float4-groups
    if (i4 >= 2048 * (XCOLS / 4)) return;
    int r = i4 / (XCOLS / 4), c4 = i4 - r * (XCOLS / 4);
    float4 s = {0.f, 0.f, 0.f, 0.f};
    #pragma unroll
    for (int z = 0; z < 8; ++z) {
        float4 v = *(const float4*)&Cpart[(size_t)z * 2048 * 256 + (size_t)r * 256 + c4 * 4];
        s.x += v.x; s.y += v.y; s.z += v.z; s.w += v.w;
    }
    *(float4*)&x_dbl[(size_t)r * XCOLS + c4 * 4] = s;
    if (c4 < DT_RANK / 4) {
        ushort4 p;
        p.x = f2bf_bits(s.x); p.y = f2bf_bits(s.y);
        p.z = f2bf_bits(s.z); p.w = f2bf_bits(s.w);
        *(ushort4*)&dtA_bf[(size_t)r * DT_RANK + c4 * 4] = p;
    }
}

// reduce 2 split-K partials -> out fp32, float4
__global__ __launch_bounds__(256)
void reduce_out(const float* __restrict__ Cpart, float* __restrict__ out)
{
    int i = blockIdx.x * 256 + threadIdx.x;          // (2048*1024)/4
    const float4* p0 = (const float4*)Cpart;
    const float4* p1 = p0 + (size_t)2048 * 1024 / 4;
    float4 a = p0[i], b = p1[i];
    float4 r; r.x = a.x + b.x; r.y = a.y + b.y; r.z = a.z + b.z; r.w = a.w + b.w;
    ((float4*)out)[i] = r;
}

// ---------------- conv + silu (short8 over d), bf16 in / bf16 out ------------
// xd is dense [B*L][D_INNER] bf16 (the x half of in_proj).
__global__ __launch_bounds__(256)
void conv_silu_kernel(const bf16* __restrict__ xd,
                      const float* __restrict__ conv_k,
                      const float* __restrict__ conv_b,
                      bf16* __restrict__ u_bf)
{
    int idx8 = blockIdx.x * 256 + threadIdx.x;       // B*L*Di/8 = 524288
    int d8 = idx8 & (D_INNER / 8 - 1);
    int t = (idx8 >> 8) & (SEQLEN - 1);
    int b = idx8 >> 18;
    float acc[8];
    {
        float4 b0 = ((const float4*)conv_b)[d8 * 2];
        float4 b1 = ((const float4*)conv_b)[d8 * 2 + 1];
        acc[0] = b0.x; acc[1] = b0.y; acc[2] = b0.z; acc[3] = b0.w;
        acc[4] = b1.x; acc[5] = b1.y; acc[6] = b1.z; acc[7] = b1.w;
    }
    #pragma unroll
    for (int k = 0; k < D_CONV; ++k) {
        int tt = t + k - (D_CONV - 1);
        if (tt >= 0) {
            short8 xv = ((const short8*)xd)[(size_t)(b * SEQLEN + tt) * (D_INNER / 8) + d8];
            float4 k0 = ((const float4*)conv_k)[k * (D_INNER / 4) + d8 * 2];
            float4 k1 = ((const float4*)conv_k)[k * (D_INNER / 4) + d8 * 2 + 1];
            acc[0] = fmaf(bfbits2f(xv[0]), k0.x, acc[0]);
            acc[1] = fmaf(bfbits2f(xv[1]), k0.y, acc[1]);
            acc[2] = fmaf(bfbits2f(xv[2]), k0.z, acc[2]);
            acc[3] = fmaf(bfbits2f(xv[3]), k0.w, acc[3]);
            acc[4] = fmaf(bfbits2f(xv[4]), k1.x, acc[4]);
            acc[5] = fmaf(bfbits2f(xv[5]), k1.y, acc[5]);
            acc[6] = fmaf(bfbits2f(xv[6]), k1.z, acc[6]);
            acc[7] = fmaf(bfbits2f(xv[7]), k1.w, acc[7]);
        }
    }
    short8 r;
    #pragma unroll
    for (int j = 0; j < 8; ++j)
        r[j] = (short)f2bf_bits(acc[j] / (1.f + __expf(-acc[j])));
    ((short8*)u_bf)[idx8] = r;
}

// ---------------- chunked scan ----------------
// dt_sb = bf16 softplus(dt_pre + b_dt) (GEMM4 epilogue).
__global__ __launch_bounds__(256)
void scan_phase1(const bf16* __restrict__ dt_sb,
                 const float* __restrict__ Aneg,
                 const bf16* __restrict__ u_bf,
                 const float* __restrict__ x_dbl,
                 float* __restrict__ Pst, float* __restrict__ Sst)
{
    __shared__ float Bsm[LCHUNK][16];
    const int d = blockIdx.x * 256 + threadIdx.x;
    const int c = blockIdx.y, b = blockIdx.z;
    const int t0 = c * LCHUNK;
    for (int i = threadIdx.x; i < LCHUNK * 16; i += 256) {   // stage B rows
        int tt = i >> 4, n = i & 15;
        Bsm[tt][n] = x_dbl[(size_t)(b * SEQLEN + t0 + tt) * XCOLS + DT_RANK + n];
    }
    float A_row[D_STATE];
    const float4* a4 = (const float4*)(Aneg + d * D_STATE);
    #pragma unroll
    for (int q = 0; q < 4; ++q) {
        float4 v = a4[q];
        A_row[q*4+0] = v.x; A_row[q*4+1] = v.y; A_row[q*4+2] = v.z; A_row[q*4+3] = v.w;
    }
    __syncthreads();
    float P[D_STATE], S[D_STATE];
    #pragma unroll
    for (int n = 0; n < D_STATE; ++n) { P[n] = 1.f; S[n] = 0.f; }
    const bf16* dpp = dt_sb + (size_t)(b * SEQLEN + t0) * D_INNER + d;
    const bf16* upp = u_bf + (size_t)(b * SEQLEN + t0) * D_INNER + d;
    #pragma unroll 4
    for (int t = 0; t < LCHUNK; ++t) {
        float dtv = __bfloat162float(dpp[(size_t)t * D_INNER]);
        float du = dtv * __bfloat162float(upp[(size_t)t * D_INNER]);
        const float4* b4 = (const float4*)&Bsm[t][0];
        #pragma unroll
        for (int q = 0; q < 4; ++q) {
            float4 v = b4[q];
            float Bn[4] = {v.x, v.y, v.z, v.w};
            #pragma unroll
            for (int e = 0; e < 4; ++e) {
                int n = q * 4 + e;
                float a = __expf(dtv * A_row[n]);
                P[n] *= a;
                S[n] = fmaf(a, S[n], du * Bn[e]);
            }
        }
    }
    const size_t base = ((size_t)(b * NCHUNK + c) * D_STATE) * D_INNER + d;
    #pragma unroll
    for (int n = 0; n < D_STATE; ++n) {
        Pst[base + (size_t)n * D_INNER] = P[n];
        Sst[base + (size_t)n * D_INNER] = S[n];
    }
}

// Phase 2: combine chunk transforms; write h_in per chunk IN-PLACE over Sst.
// All loads address-independent: preload into regs, chain in-register.
__global__ __launch_bounds__(256)
void scan_phase2(const float* __restrict__ Pst, float* __restrict__ Sst)
{
    const int d = blockIdx.x * 256 + threadIdx.x;
    const int n = blockIdx.y;
    const int b = blockIdx.z;
    float Pv[NCHUNK], Sv[NCHUNK];
    #pragma unroll
    for (int c = 0; c < NCHUNK; ++c) {
        const size_t idx = ((size_t)(b * NCHUNK + c) * D_STATE + n) * D_INNER + d;
        Pv[c] = Pst[idx];
        Sv[c] = Sst[idx];
    }
    float h = 0.f;
    #pragma unroll
    for (int c = 0; c < NCHUNK; ++c) {
        float hin = h;
        h = fmaf(Pv[c], h, Sv[c]);
        Sv[c] = hin;                        // h_in for chunk c
    }
    #pragma unroll
    for (int c = 0; c < NCHUNK; ++c) {
        const size_t idx = ((size_t)(b * NCHUNK + c) * D_STATE + n) * D_INNER + d;
        Sst[idx] = Sv[c];
    }
}

__global__ __launch_bounds__(256)
void scan_phase3(const bf16* __restrict__ dt_sb,
                 const float* __restrict__ Aneg,
                 const bf16* __restrict__ u_bf,
                 const float* __restrict__ x_dbl,
                 const float* __restrict__ Dvec,
                 const bf16* __restrict__ sz_bf,  // silu(z), bf16
                 const float* __restrict__ hin,   // == Sst after phase2
                 bf16* __restrict__ g_bf)
{
    __shared__ float BCs[LCHUNK][32];
    const int d = blockIdx.x * 256 + threadIdx.x;
    const int c = blockIdx.y, b = blockIdx.z;
    const int t0 = c * LCHUNK;
    for (int i = threadIdx.x; i < LCHUNK * 32; i += 256) {   // stage B and C rows
        int tt = i >> 5, col = i & 31;
        BCs[tt][col] = x_dbl[(size_t)(b * SEQLEN + t0 + tt) * XCOLS + DT_RANK + col];
    }
    float A_row[D_STATE];
    const float4* a4 = (const float4*)(Aneg + d * D_STATE);
    #pragma unroll
    for (int q = 0; q < 4; ++q) {
        float4 v = a4[q];
        A_row[q*4+0] = v.x; A_row[q*4+1] = v.y; A_row[q*4+2] = v.z; A_row[q*4+3] = v.w;
    }
    const float Dd = Dvec[d];
    __syncthreads();
    float h[D_STATE];
    const size_t base = ((size_t)(b * NCHUNK + c) * D_STATE) * D_INNER + d;
    #pragma unroll
    for (int n = 0; n < D_STATE; ++n) h[n] = hin[base + (size_t)n * D_INNER];
    const bf16* dpp = dt_sb + (size_t)(b * SEQLEN + t0) * D_INNER + d;
    const bf16* upp = u_bf + (size_t)(b * SEQLEN + t0) * D_INNER + d;
    const bf16* zpp = sz_bf + (size_t)(b * SEQLEN + t0) * D_INNER + d;
    bf16* gpp = g_bf + (size_t)(b * SEQLEN + t0) * D_INNER + d;
    #pragma unroll 4
    for (int t = 0; t < LCHUNK; ++t) {
        float dtv = __bfloat162float(dpp[(size_t)t * D_INNER]);
        float uv = __bfloat162float(upp[(size_t)t * D_INNER]);
        float sz = __bfloat162float(zpp[(size_t)t * D_INNER]);
        float du = dtv * uv;
        float y = 0.f;
        const float4* bc4 = (const float4*)&BCs[t][0];
        #pragma unroll
        for (int q = 0; q < 4; ++q) {
            float4 v = bc4[q];
            float4 w = bc4[q + 4];
            float Bn[4] = {v.x, v.y, v.z, v.w};
            float Cn[4] = {w.x, w.y, w.z, w.w};
            #pragma unroll
            for (int e = 0; e < 4; ++e) {
                int n = q * 4 + e;
                float a = __expf(dtv * A_row[n]);
                h[n] = fmaf(a, h[n], du * Bn[e]);
                y = fmaf(h[n], Cn[e], y);
            }
        }
        float gy = y + uv * Dd;
        gpp[(size_t)t * D_INNER] = __float2bfloat16(gy * sz);
    }
}

extern "C" void kernel_launch(void* const* d_in, const int* in_sizes, int n_in,
                              void* d_out, int out_size, void* d_ws, size_t ws_size,
                              hipStream_t stream)
{
    const float* x      = (const float*)d_in[0];
    const float* W_in   = (const float*)d_in[1];
    const float* conv_k = (const float*)d_in[2];
    const float* conv_b = (const float*)d_in[3];
    const float* W_xproj= (const float*)d_in[4];
    const float* W_dt   = (const float*)d_in[5];
    const float* b_dt   = (const float*)d_in[6];
    const float* A_log  = (const float*)d_in[7];
    const float* Dvec   = (const float*)d_in[8];
    const float* W_out  = (const float*)d_in[9];
    float* out = (float*)d_out;

    const int BL = BATCH * SEQLEN;                    // 2048

    // fp32 region
    float* ws     = (float*)d_ws;
    float* x_dbl  = ws;                                 //   327,680
    float* Pst    = x_dbl + (size_t)BL * XCOLS;         // 2,097,152
    float* Sst    = Pst + (size_t)BATCH * NCHUNK * D_STATE * D_INNER;   // 2,097,152
    float* Aneg   = Sst + (size_t)BATCH * NCHUNK * D_STATE * D_INNER;   //    32,768
    float* Cpart  = Aneg + 32768;                       // 4,194,304 floats (GEMM3: 8x2048x256; GEMM6: 2x2048x1024)
    bf16*  x_bf   = (bf16*)Cpart;                       // 2048x1024, dead before GEMM3
    // bf16 region
    bf16* Win_t  = (bf16*)(Cpart + (size_t)4 * 1048576);// 4096 x 1024
    bf16* xd_bf  = Win_t + (size_t)4096 * 1024;         // 2048 x 2048 (x half, bf16)
    bf16* u_bf   = xd_bf + (size_t)BL * D_INNER;        // 2048 x 2048
    bf16* sz_bf  = u_bf  + (size_t)BL * D_INNER;        // 2048 x 2048 (silu(z))
    bf16* Wxp_t  = sz_bf + (size_t)BL * D_INNER;        // 256  x 2048 (padded)
    bf16* dtA_bf = Wxp_t + (size_t)256 * 2048;          // 2048 x 128
    bf16* Wdt_t  = dtA_bf+ (size_t)BL * DT_RANK;        // 2048 x 128
    bf16* g_bf   = Wdt_t + (size_t)2048 * 128;          // 2048 x 2048
    bf16* Wout_t = g_bf  + (size_t)BL * D_INNER;        // 1024 x 2048
    bf16* dt_sb  = Wout_t+ (size_t)1024 * 2048;         // 2048 x 2048

    // 0) fused prep: 4 transposes + x convert + Aneg
    prep_kernel<<<4096 + 512 + 256 + 2048 + 2048 + 128, 256, 0, stream>>>(
        x, x_bf, W_in, Win_t, W_xproj, Wxp_t, W_dt, Wdt_t, W_out, Wout_t, A_log, Aneg);

    // 1) in_proj: BN=128/BK=64, 512 threads -> 512 blocks = 2/CU, 4 waves/SIMD
    gemm_mfma<128, 2><<<dim3(32, 16, 1), 512, 0, stream>>>(
        x_bf, Win_t, nullptr, sz_bf, xd_bf, nullptr, BL, 2 * D_INNER, D_MODEL, D_INNER, D_MODEL);

    // 2) u_bf = bf16(silu(causal_conv(xd_bf) + b))
    conv_silu_kernel<<<(BL * D_INNER / 8) / 256, 256, 0, stream>>>(xd_bf, conv_k, conv_b, u_bf);

    // 3) x_dbl = u @ W_xproj  split-K 8, BN=64, 3 col-blocks (cols 0..191 cover 160)
    gemm_mfma<64, 0><<<dim3(3, 16, 8), 512, 0, stream>>>(
        u_bf, Wxp_t, Cpart, nullptr, nullptr, nullptr, BL, 256, D_INNER, 256, 256);
    reduce_xdbl<<<(BL * (XCOLS / 4) + 255) / 256, 256, 0, stream>>>(Cpart, x_dbl, dtA_bf);

    // 4) dt_sb = bf16(softplus(dt_low @ W_dt + b_dt)), BN=64 -> 512 blocks
    gemm_mfma<64, 1><<<dim3(32, 16, 1), 512, 0, stream>>>(
        dtA_bf, Wdt_t, nullptr, dt_sb, nullptr, b_dt, BL, D_INNER, DT_RANK, D_INNER, DT_RANK);

    // 5) chunked selective scan -> g_bf = bf16((y + u*D) * silu(z))
    scan_phase1<<<dim3(D_INNER / 256, NCHUNK, BATCH), 256, 0, stream>>>(
        dt_sb, Aneg, u_bf, x_dbl, Pst, Sst);
    scan_phase2<<<dim3(D_INNER / 256, D_STATE, BATCH), 256, 0, stream>>>(Pst, Sst);
    scan_phase3<<<dim3(D_INNER / 256, NCHUNK, BATCH), 256, 0, stream>>>(
        dt_sb, Aneg, u_bf, x_dbl, Dvec, sz_bf, Sst, g_bf);

    // 6) out = g @ W_out  split-K 2, BN=64 -> 512 blocks
    gemm_mfma<64, 0><<<dim3(16, 16, 2), 512, 0, stream>>>(
        g_bf, Wout_t, Cpart, nullptr, nullptr, nullptr, BL, D_MODEL, D_INNER, D_MODEL, D_INNER / 2);
    reduce_out<<<(BL * D_MODEL / 4) / 256, 256, 0, stream>>>(Cpart, out);
}